// Round 6
// baseline (575.411 us; speedup 1.0000x reference)
//
#include <hip/hip_runtime.h>
#include <math.h>

typedef unsigned short u16;
typedef short bf16x8 __attribute__((ext_vector_type(8)));
typedef float f32x4 __attribute__((ext_vector_type(4)));

#define NRAYS 4096
#define NSAMP 128
#define NPTS (NRAYS * NSAMP)
#define TBL_MASK 0x7FFFFu
#define LVL_STRIDE (524288 * 2)

// d_ws u16-element offsets: sigma weights in 3-way split (h/m/l), then color
#define SB_W0H 0        // [64][32] x3
#define SB_W0M 2048
#define SB_W0L 4096
#define SB_W1H 6144     // [64][64] x3
#define SB_W1M 10240
#define SB_W1L 14336
#define SB_W2H 18432    // [16][64] x3
#define SB_W2M 19456
#define SB_W2L 20480
#define WB_C0 21504     // [64][64] remapped rows
#define WB_C1 25600
#define WB_C2 29696
#define WB_C3 33792     // [16][64]
#define RAW_OFF 131072  // byte offset of raw (bf16x4/point = 4 MB)

#define MEMBAR() asm volatile("" ::: "memory")

struct ResArr { float r[16]; };
template<int N> struct IC { static constexpr int value = N; };

__device__ __forceinline__ u16 f2b(float f) {   // RNE f32->bf16
  unsigned u = __float_as_uint(f);
  unsigned r = u + 0x7FFFu + ((u >> 16) & 1u);
  return (u16)(r >> 16);
}
__device__ __forceinline__ unsigned pack2(float lo, float hi) {
  return (unsigned)f2b(lo) | ((unsigned)f2b(hi) << 16);
}
__device__ __forceinline__ float b2f(u16 u) {
  return __uint_as_float(((unsigned)u) << 16);
}
// SP-th term of the 3-way bf16 split x = h + m + l + O(2^-24 x)
template<int SP>
__device__ __forceinline__ u16 splitb(float x) {
  u16 h = f2b(x);
  if (SP == 0) return h;
  float r = x - b2f(h);          // exact (Sterbenz)
  u16 m = f2b(r);
  if (SP == 1) return m;
  return f2b(r - b2f(m));
}
__device__ __forceinline__ float sigmoidf_(float x) { return 1.f / (1.f + expf(-x)); }

// ---------------- prep: probe k-map, split+transpose sigma w, pack color w ----------------
__global__ void __launch_bounds__(256)
prep_kernel(const float* __restrict__ ws0, const float* __restrict__ ws1,
            const float* __restrict__ ws2, const float* __restrict__ wc0,
            const float* __restrict__ wc1, const float* __restrict__ wc2,
            const float* __restrict__ wc3, u16* __restrict__ wb)
{
  __shared__ int P[32];
  __shared__ int Pinv[32];
  const int t = threadIdx.x;
  if (t < 64) {
    const int g = t >> 4;
    for (int tt = 0; tt < 32; ++tt) {
      bf16x8 A, B;
      #pragma unroll
      for (int e = 0; e < 8; ++e) {
        A[e] = (short)f2b((float)(g * 8 + e + 1));
        B[e] = (short)((g * 8 + e == tt) ? 0x3F80 : 0);
      }
      f32x4 c = {0.f, 0.f, 0.f, 0.f};
      c = __builtin_amdgcn_mfma_f32_16x16x32_bf16(A, B, c, 0, 0, 0);
      if (t == 0) P[tt] = (int)(c[0] + 0.5f) - 1;
    }
  }
  __syncthreads();
  if (t < 32) Pinv[t] = t;
  __syncthreads();
  if (t < 32) { int p = P[t]; if (p >= 0 && p < 32) Pinv[p] = t; }
  __syncthreads();

  // sigma weights: [out][in] with Pinv k-permutation, 3-way split
  for (int i = t; i < 2048; i += 256) {
    int o = i >> 5, k = i & 31, kt = Pinv[k];
    float v = ws0[kt * 64 + o];
    u16 h = f2b(v); float r = v - b2f(h); u16 m = f2b(r); u16 l = f2b(r - b2f(m));
    wb[SB_W0H + i] = h; wb[SB_W0M + i] = m; wb[SB_W0L + i] = l;
  }
  for (int i = t; i < 4096; i += 256) {
    int o = i >> 6, k = i & 63, kt = (k & 32) | Pinv[k & 31];
    float v = ws1[kt * 64 + o];
    u16 h = f2b(v); float r = v - b2f(h); u16 m = f2b(r); u16 l = f2b(r - b2f(m));
    wb[SB_W1H + i] = h; wb[SB_W1M + i] = m; wb[SB_W1L + i] = l;
  }
  for (int i = t; i < 1024; i += 256) {
    int o = i >> 6, k = i & 63, kt = (k & 32) | Pinv[k & 31];
    float v = ws2[kt * 16 + o];
    u16 h = f2b(v); float r = v - b2f(h); u16 m = f2b(r); u16 l = f2b(r - b2f(m));
    wb[SB_W2H + i] = h; wb[SB_W2M + i] = m; wb[SB_W2L + i] = l;
  }
  // color layer 0: cin slots 0..15 encd, 16 dead(sigma), 17..31 geo(1..15),
  // 32..47 app, 48..63 zero  ->  wc0 rows: s<16 -> s; 17..47 -> s-1; else 0
  for (int i = t; i < 4096; i += 256) {
    int o = i >> 6, s = i & 63, kt = (s & 32) | Pinv[s & 31];
    float v = 0.f;
    if (kt < 16) v = wc0[kt * 64 + o];
    else if (kt >= 17 && kt <= 47) v = wc0[(kt - 1) * 64 + o];
    wb[WB_C0 + i] = f2b(v);
  }
  for (int i = t; i < 4096; i += 256) {
    int o = i >> 6, s = i & 63, kt = (s & 32) | Pinv[s & 31];
    wb[WB_C1 + i] = f2b(wc1[kt * 64 + o]);
  }
  for (int i = t; i < 4096; i += 256) {
    int o = i >> 6, s = i & 63, kt = (s & 32) | Pinv[s & 31];
    wb[WB_C2 + i] = f2b(wc2[kt * 64 + o]);
  }
  for (int i = t; i < 1024; i += 256) {
    int o = i >> 6, s = i & 63, kt = (s & 32) | Pinv[s & 31];
    wb[WB_C3 + i] = f2b(o < 3 ? wc3[kt * 3 + o] : 0.f);
  }
}

// one MFMA pass over the B-split currently in buf; accumulates NASP A-splits
template<int NM, int NKC, int NASP>
__device__ __forceinline__ void sigma_pass(const char* buf, const u16* __restrict__ wb,
                                           int offH, int offM, int offL,
                                           f32x4 (&acc)[4][NM], int q, int g, unsigned fswz)
{
  #pragma unroll
  for (int n = 0; n < 4; ++n) {
    bf16x8 b[NKC];
    #pragma unroll
    for (int kc = 0; kc < NKC; ++kc)
      b[kc] = *(const bf16x8*)(buf + (n * 16 + q) * 128 + (((unsigned)(kc * 64 + g * 16)) ^ fswz));
    #pragma unroll
    for (int m = 0; m < NM; ++m) {
      const int arow = (NM == 1 ? q : m * 16 + q);
      #pragma unroll
      for (int asp = 0; asp < NASP; ++asp) {
        const u16* Wp = wb + (asp == 0 ? offH : (asp == 1 ? offM : offL));
        #pragma unroll
        for (int kc = 0; kc < NKC; ++kc) {
          bf16x8 A = *(const bf16x8*)(Wp + arow * (NKC * 32) + kc * 32 + g * 8);
          acc[n][m] = __builtin_amdgcn_mfma_f32_16x16x32_bf16(A, b[kc], acc[n][m], 0, 0, 0);
        }
      }
    }
  }
}

// ---------------- fused encode + split-MFMA sigma MLP + bf16 MFMA color MLP ----------------
__global__ void __launch_bounds__(256, 3)
point_kernel(const float* __restrict__ rays, const float* __restrict__ tables,
             const u16* __restrict__ wb, const float* __restrict__ app_table,
             u16* __restrict__ raw, ResArr RES)
{
  __shared__ char lds[4 * 8192 + 4 * 256];
  const int t = threadIdx.x, wv = t >> 6, lane = t & 63;
  char* buf = lds + wv * 8192;
  float* keepb = (float*)(lds + 32768 + wv * 256);
  const int pBase = blockIdx.x * 256 + wv * 64;
  const int q = lane & 15, g = lane >> 4;
  const unsigned fswz = (unsigned)((q & 7) << 4);
  const unsigned myswz = (unsigned)((lane & 7) << 4);

  // ---------- phase 1: per-thread hash encode ----------
  const int ptG = pBase + lane;
  const int r = ptG >> 7, s = ptG & (NSAMP - 1);
  const float ox = rays[r * 7 + 0], oy = rays[r * 7 + 1], oz = rays[r * 7 + 2];
  const float dx = rays[r * 7 + 3], dy = rays[r * 7 + 4], dz = rays[r * 7 + 5];
  const int code = (int)rays[r * 7 + 6];
  const float z = 0.5f + (3.5f / 127.f) * (float)s;
  const float x = fmaf(dx, z, ox), y = fmaf(dy, z, oy), w = fmaf(dz, z, oz);
  const bool keep = (x >= -4.f && x <= 4.f && y >= -4.f && y <= 4.f &&
                     w >= -4.f && w <= 4.f);
  const float xc = fminf(fmaxf(x, -4.f), 4.f);
  const float yc = fminf(fmaxf(y, -4.f), 4.f);
  const float zc = fminf(fmaxf(w, -4.f), 4.f);

  float encp[32];
  #pragma unroll
  for (int l = 0; l < 16; ++l) {
    const float res = RES.r[l];
    const float sc = res * 0.125f;
    const float px = (xc + 4.f) * sc, py = (yc + 4.f) * sc, pz = (zc + 4.f) * sc;
    const float bx = floorf(px), by = floorf(py), bz = floorf(pz);
    const float fx = px - bx, fy = py - by, fz = pz - bz;
    const unsigned ix = (unsigned)bx, iy = (unsigned)by, iz = (unsigned)bz;
    const unsigned hx0 = ix, hx1 = ix + 1u;
    const unsigned hy0 = iy * 2654435761u, hy1 = (iy + 1u) * 2654435761u;
    const unsigned hz0 = iz * 805459861u,  hz1 = (iz + 1u) * 805459861u;
    const float wx0 = 1.f - fx, wy0 = 1.f - fy, wz0 = 1.f - fz;
    const float* tl = tables + (size_t)l * LVL_STRIDE;
    float f0 = 0.f, f1 = 0.f;
    #pragma unroll
    for (int c = 0; c < 8; ++c) {
      const unsigned cx = (c >> 2) & 1, cy = (c >> 1) & 1, cz = c & 1;
      const unsigned idx = ((cx ? hx1 : hx0) ^ (cy ? hy1 : hy0) ^ (cz ? hz1 : hz0)) & TBL_MASK;
      const float cw = (cx ? fx : wx0) * (cy ? fy : wy0) * (cz ? fz : wz0);
      const float2 e = *reinterpret_cast<const float2*>(tl + (size_t)idx * 2);
      f0 = fmaf(cw, e.x, f0);
      f1 = fmaf(cw, e.y, f1);
    }
    encp[2 * l] = f0;
    encp[2 * l + 1] = f1;
  }
  keepb[lane] = keep ? 1.f : 0.f;

  // ---------- phase 2: sigma MLP via 3-way-split MFMA ----------
  // fill own row (=lane) with SP-split of encp (32 slots, bytes 0..63)
  auto fillEnc = [&](auto SPc) {
    constexpr int SP = decltype(SPc)::value;
    #pragma unroll
    for (int c = 0; c < 4; ++c) {
      uint4 u;
      u.x = (unsigned)splitb<SP>(encp[8 * c + 0]) | ((unsigned)splitb<SP>(encp[8 * c + 1]) << 16);
      u.y = (unsigned)splitb<SP>(encp[8 * c + 2]) | ((unsigned)splitb<SP>(encp[8 * c + 3]) << 16);
      u.z = (unsigned)splitb<SP>(encp[8 * c + 4]) | ((unsigned)splitb<SP>(encp[8 * c + 5]) << 16);
      u.w = (unsigned)splitb<SP>(encp[8 * c + 6]) | ((unsigned)splitb<SP>(encp[8 * c + 7]) << 16);
      *(uint4*)(buf + lane * 128 + (((unsigned)(c * 16)) ^ myswz)) = u;
    }
  };
  // fill from C-regs: lane (q,g) holds channels m*16+4g..+3 of points n*16+q
  auto fillC = [&](const f32x4 (&a)[4][4], auto SPc) {
    constexpr int SP = decltype(SPc)::value;
    #pragma unroll
    for (int n = 0; n < 4; ++n)
      #pragma unroll
      for (int m = 0; m < 4; ++m) {
        uint2 u;
        u.x = (unsigned)splitb<SP>(a[n][m][0]) | ((unsigned)splitb<SP>(a[n][m][1]) << 16);
        u.y = (unsigned)splitb<SP>(a[n][m][2]) | ((unsigned)splitb<SP>(a[n][m][3]) << 16);
        *(uint2*)(buf + (n * 16 + q) * 128 + (((unsigned)(m * 32 + g * 8)) ^ fswz)) = u;
      }
  };

  f32x4 acc0[4][4];
  #pragma unroll
  for (int n = 0; n < 4; ++n)
    #pragma unroll
    for (int m = 0; m < 4; ++m) acc0[n][m] = f32x4{0.f, 0.f, 0.f, 0.f};

  fillEnc(IC<0>{}); MEMBAR();
  sigma_pass<4, 1, 3>(buf, wb, SB_W0H, SB_W0M, SB_W0L, acc0, q, g, fswz); MEMBAR();
  fillEnc(IC<1>{}); MEMBAR();
  sigma_pass<4, 1, 2>(buf, wb, SB_W0H, SB_W0M, SB_W0L, acc0, q, g, fswz); MEMBAR();
  fillEnc(IC<2>{}); MEMBAR();
  sigma_pass<4, 1, 1>(buf, wb, SB_W0H, SB_W0M, SB_W0L, acc0, q, g, fswz); MEMBAR();
  #pragma unroll
  for (int n = 0; n < 4; ++n)
    #pragma unroll
    for (int m = 0; m < 4; ++m)
      #pragma unroll
      for (int j = 0; j < 4; ++j) acc0[n][m][j] = fmaxf(acc0[n][m][j], 0.f);

  f32x4 acc1[4][4];
  #pragma unroll
  for (int n = 0; n < 4; ++n)
    #pragma unroll
    for (int m = 0; m < 4; ++m) acc1[n][m] = f32x4{0.f, 0.f, 0.f, 0.f};

  fillC(acc0, IC<0>{}); MEMBAR();
  sigma_pass<4, 2, 3>(buf, wb, SB_W1H, SB_W1M, SB_W1L, acc1, q, g, fswz); MEMBAR();
  fillC(acc0, IC<1>{}); MEMBAR();
  sigma_pass<4, 2, 2>(buf, wb, SB_W1H, SB_W1M, SB_W1L, acc1, q, g, fswz); MEMBAR();
  fillC(acc0, IC<2>{}); MEMBAR();
  sigma_pass<4, 2, 1>(buf, wb, SB_W1H, SB_W1M, SB_W1L, acc1, q, g, fswz); MEMBAR();
  #pragma unroll
  for (int n = 0; n < 4; ++n)
    #pragma unroll
    for (int m = 0; m < 4; ++m)
      #pragma unroll
      for (int j = 0; j < 4; ++j) acc1[n][m][j] = fmaxf(acc1[n][m][j], 0.f);

  f32x4 acc2[4][1];
  #pragma unroll
  for (int n = 0; n < 4; ++n) acc2[n][0] = f32x4{0.f, 0.f, 0.f, 0.f};

  fillC(acc1, IC<0>{}); MEMBAR();
  sigma_pass<1, 2, 3>(buf, wb, SB_W2H, SB_W2M, SB_W2L, acc2, q, g, fswz); MEMBAR();
  fillC(acc1, IC<1>{}); MEMBAR();
  sigma_pass<1, 2, 2>(buf, wb, SB_W2H, SB_W2M, SB_W2L, acc2, q, g, fswz); MEMBAR();
  fillC(acc1, IC<2>{}); MEMBAR();
  sigma_pass<1, 2, 1>(buf, wb, SB_W2H, SB_W2M, SB_W2L, acc2, q, g, fswz); MEMBAR();

  // sigma (lane g==0 holds channel 0 of point n*16+q); geo -> color slots 16+4g..19+4g
  float sigv[4];
  #pragma unroll
  for (int n = 0; n < 4; ++n) {
    sigv[n] = acc2[n][0][0] * keepb[n * 16 + q];   // meaningful on g==0 lanes
    uint2 u;
    u.x = pack2(acc2[n][0][0], acc2[n][0][1]);     // slot16 weight row is zero
    u.y = pack2(acc2[n][0][2], acc2[n][0][3]);
    *(uint2*)(buf + (n * 16 + q) * 128 + (((unsigned)(32 + 8 * g)) ^ fswz)) = u;
  }

  // own row: encd slots 0..15, app 32..47, zeros 48..63
  {
    const float xx = dx * dx, yy = dy * dy, zz2 = dz * dz;
    const float xy = dx * dy, yz = dy * dz, xz = dx * dz;
    float e0 = 0.28209479177387814f;
    float e1 = -0.4886025119029199f * dy;
    float e2 = 0.4886025119029199f * dz;
    float e3 = -0.4886025119029199f * dx;
    float e4 = 1.0925484305920792f * xy;
    float e5 = -1.0925484305920792f * yz;
    float e6 = 0.31539156525252005f * (2.f * zz2 - xx - yy);
    float e7 = -1.0925484305920792f * xz;
    float e8 = 0.5462742152960396f * (xx - yy);
    float e9 = -0.5900435899266435f * dy * (3.f * xx - yy);
    float e10 = 2.890611442640554f * xy * dz;
    float e11 = -0.4570457994644658f * dy * (4.f * zz2 - xx - yy);
    float e12 = 0.3731763325901154f * dz * (2.f * zz2 - 3.f * xx - 3.f * yy);
    float e13 = -0.4570457994644658f * dx * (4.f * zz2 - xx - yy);
    float e14 = 1.445305721320277f * dz * (xx - yy);
    float e15 = -0.5900435899266435f * dx * (xx - 3.f * yy);
    uint4 u0; u0.x = pack2(e0, e1);  u0.y = pack2(e2, e3);  u0.z = pack2(e4, e5);  u0.w = pack2(e6, e7);
    uint4 u1; u1.x = pack2(e8, e9);  u1.y = pack2(e10, e11); u1.z = pack2(e12, e13); u1.w = pack2(e14, e15);
    *(uint4*)(buf + lane * 128 + (0u ^ myswz)) = u0;
    *(uint4*)(buf + lane * 128 + (16u ^ myswz)) = u1;
    const float4* ap = (const float4*)(app_table + (size_t)code * 16);
    float4 a0 = ap[0], a1 = ap[1], a2 = ap[2], a3 = ap[3];
    uint4 v0; v0.x = pack2(a0.x, a0.y); v0.y = pack2(a0.z, a0.w); v0.z = pack2(a1.x, a1.y); v0.w = pack2(a1.z, a1.w);
    uint4 v1; v1.x = pack2(a2.x, a2.y); v1.y = pack2(a2.z, a2.w); v1.z = pack2(a3.x, a3.y); v1.w = pack2(a3.z, a3.w);
    *(uint4*)(buf + lane * 128 + (64u ^ myswz)) = v0;
    *(uint4*)(buf + lane * 128 + (80u ^ myswz)) = v1;
    uint4 zv; zv.x = 0u; zv.y = 0u; zv.z = 0u; zv.w = 0u;
    *(uint4*)(buf + lane * 128 + (96u ^ myswz)) = zv;
    *(uint4*)(buf + lane * 128 + (112u ^ myswz)) = zv;
  }
  MEMBAR();

  // ---------- phase 3: color MFMA MLP (plain bf16, proven) ----------
  auto rdB = [&](int n, int kc) -> bf16x8 {
    return *(const bf16x8*)(buf + (n * 16 + q) * 128 + (((unsigned)(kc * 64 + g * 16)) ^ fswz));
  };
  auto ldA = [&](const u16* Wp, int row, int kc) -> bf16x8 {
    return *(const bf16x8*)(Wp + row * 64 + kc * 32 + g * 8);
  };
  auto wrC = [&](int n, int slot0, f32x4 c) {
    c[0] = fmaxf(c[0], 0.f); c[1] = fmaxf(c[1], 0.f);
    c[2] = fmaxf(c[2], 0.f); c[3] = fmaxf(c[3], 0.f);
    uint2 u; u.x = pack2(c[0], c[1]); u.y = pack2(c[2], c[3]);
    *(uint2*)(buf + (n * 16 + q) * 128 + (((unsigned)(slot0 * 2)) ^ fswz)) = u;
  };
  auto layer64 = [&](const u16* Wp) {
    bf16x8 A[4][2];
    #pragma unroll
    for (int m = 0; m < 4; ++m) {
      A[m][0] = ldA(Wp, m * 16 + q, 0);
      A[m][1] = ldA(Wp, m * 16 + q, 1);
    }
    #pragma unroll
    for (int n = 0; n < 4; ++n) {
      bf16x8 b0 = rdB(n, 0), b1 = rdB(n, 1);
      #pragma unroll
      for (int m = 0; m < 4; ++m) {
        f32x4 c = f32x4{0.f, 0.f, 0.f, 0.f};
        c = __builtin_amdgcn_mfma_f32_16x16x32_bf16(A[m][0], b0, c, 0, 0, 0);
        c = __builtin_amdgcn_mfma_f32_16x16x32_bf16(A[m][1], b1, c, 0, 0, 0);
        wrC(n, m * 16 + g * 4, c);
      }
    }
    MEMBAR();
  };

  layer64(wb + WB_C0);
  layer64(wb + WB_C1);
  layer64(wb + WB_C2);

  {
    const u16* Wp = wb + WB_C3;
    bf16x8 A0 = ldA(Wp, q, 0), A1 = ldA(Wp, q, 1);
    #pragma unroll
    for (int n = 0; n < 4; ++n) {
      bf16x8 b0 = rdB(n, 0), b1 = rdB(n, 1);
      f32x4 c = f32x4{0.f, 0.f, 0.f, 0.f};
      c = __builtin_amdgcn_mfma_f32_16x16x32_bf16(A0, b0, c, 0, 0, 0);
      c = __builtin_amdgcn_mfma_f32_16x16x32_bf16(A1, b1, c, 0, 0, 0);
      if (g == 0) {
        uint2 o; o.x = pack2(c[0], c[1]); o.y = pack2(c[2], sigv[n]);
        *(uint2*)(raw + (size_t)(pBase + n * 16 + q) * 4) = o;
      }
    }
  }
}

// ---------------- per-ray compositing ----------------
__global__ void __launch_bounds__(256)
render_kernel(const float* __restrict__ rays, const u16* __restrict__ raw,
              float* __restrict__ out)
{
  const int r = blockIdx.x * 256 + threadIdx.x;
  if (r >= NRAYS) return;
  const float dx = rays[r * 7 + 3], dy = rays[r * 7 + 4], dz = rays[r * 7 + 5];
  const float nrm = sqrtf(dx * dx + dy * dy + dz * dz);
  const float dstep = 3.5f / 127.f;
  const ushort4* rp = reinterpret_cast<const ushort4*>(raw) + (size_t)r * NSAMP;

  float T = 1.f, sumw = 0.f, sumwz = 0.f, cm0 = 0.f, cm1 = 0.f, cm2 = 0.f;
  for (int s = 0; s < NSAMP; ++s) {
    const ushort4 rw = rp[s];
    const float dist = ((s < NSAMP - 1) ? dstep : 1e10f) * nrm;
    const float sigv = fmaxf(b2f(rw.w), 0.f);
    const float alpha = 1.f - expf(-sigv * dist);
    const float wgt = alpha * T;
    T *= (1.f - alpha + 1e-10f);
    const float zv = 0.5f + dstep * (float)s;
    sumw += wgt;
    sumwz = fmaf(wgt, zv, sumwz);
    cm0 = fmaf(wgt, sigmoidf_(b2f(rw.x)), cm0);
    cm1 = fmaf(wgt, sigmoidf_(b2f(rw.y)), cm1);
    cm2 = fmaf(wgt, sigmoidf_(b2f(rw.z)), cm2);
  }

  float S1 = 0.f, S2 = 0.f, T2 = 1.f;
  for (int s = 0; s < NSAMP; ++s) {
    const ushort4 rw = rp[s];
    const float dist = ((s < NSAMP - 1) ? dstep : 1e10f) * nrm;
    const float sigv = fmaxf(b2f(rw.w), 0.f);
    const float alpha = 1.f - expf(-sigv * dist);
    const float wgt = alpha * T2;
    T2 *= (1.f - alpha + 1e-10f);
    const float qv = fmaxf(wgt, 1e-12f);
    S1 += qv;
    S2 = fmaf(qv, logf(qv), S2);
  }
  const float plast = fmaxf(1.f - sumw + 1e-6f, 1e-12f);
  S1 += plast;
  S2 = fmaf(plast, logf(plast), S2);
  const float ent = logf(S1) - S2 / S1;

  out[r * 3 + 0] = cm0;
  out[r * 3 + 1] = cm1;
  out[r * 3 + 2] = cm2;
  out[NRAYS * 3 + r] = sumwz;
  out[NRAYS * 4 + r] = ent;
}

extern "C" void kernel_launch(void* const* d_in, const int* in_sizes, int n_in,
                              void* d_out, int out_size, void* d_ws, size_t ws_size,
                              hipStream_t stream)
{
  const float* rays   = (const float*)d_in[0];
  const float* tables = (const float*)d_in[2];
  const float* ws0    = (const float*)d_in[3];
  const float* ws1    = (const float*)d_in[4];
  const float* ws2    = (const float*)d_in[5];
  const float* wc0    = (const float*)d_in[6];
  const float* wc1    = (const float*)d_in[7];
  const float* wc2    = (const float*)d_in[8];
  const float* wc3    = (const float*)d_in[9];
  const float* app    = (const float*)d_in[10];

  u16* wb  = (u16*)d_ws;
  u16* raw = (u16*)((char*)d_ws + RAW_OFF);
  float* out = (float*)d_out;

  ResArr RES;
  const double b = exp((log(512.0) - log(16.0)) / 15.0);
  for (int l = 0; l < 16; ++l) RES.r[l] = (float)floor(16.0 * pow(b, (double)l));

  hipLaunchKernelGGL(prep_kernel, dim3(1), dim3(256), 0, stream,
                     ws0, ws1, ws2, wc0, wc1, wc2, wc3, wb);
  hipLaunchKernelGGL(point_kernel, dim3(NPTS / 256), dim3(256), 0, stream,
                     rays, tables, wb, app, raw, RES);
  hipLaunchKernelGGL(render_kernel, dim3(16), dim3(256), 0, stream,
                     rays, raw, out);
}

// Round 7
// 333.687 us; speedup vs baseline: 1.7244x; 1.7244x over previous
//
#include <hip/hip_runtime.h>
#include <math.h>

typedef unsigned short u16;
typedef short bf16x8 __attribute__((ext_vector_type(8)));
typedef float f32x4 __attribute__((ext_vector_type(4)));

#define NRAYS 4096
#define NSAMP 128
#define NPTS (NRAYS * NSAMP)
#define TBL_MASK 0x7FFFFu
#define LVL_STRIDE (524288 * 2)

// d_ws u16-element offsets
#define SB_W0H 0        // [64][32] x3 splits
#define SB_W0M 2048
#define SB_W0L 4096
#define SB_W1H 6144     // [64][64] x3 splits
#define SB_W1M 10240
#define SB_W1L 14336
#define WB_G   18432    // [16][64] plain bf16 W2 (geo; row0=sigma, dead via zero slot16)
#define WB_C0  19456    // [64][64] remapped rows
#define WB_C1  23552
#define WB_C2  27648
#define WB_C3  31744    // [16][64]
#define RAW_OFF 131072  // byte offset of raw (bf16x4/point = 4 MB)

#define MEMBAR() asm volatile("" ::: "memory")

struct ResArr { float r[16]; };

__device__ __forceinline__ u16 f2b(float f) {   // RNE f32->bf16
  unsigned u = __float_as_uint(f);
  unsigned r = u + 0x7FFFu + ((u >> 16) & 1u);
  return (u16)(r >> 16);
}
__device__ __forceinline__ unsigned pack2(float lo, float hi) {
  return (unsigned)f2b(lo) | ((unsigned)f2b(hi) << 16);
}
__device__ __forceinline__ float b2f(u16 u) {
  return __uint_as_float(((unsigned)u) << 16);
}
__device__ __forceinline__ void split3(float x, u16& h, u16& m, u16& l) {
  h = f2b(x);
  float r = x - b2f(h);      // exact (Sterbenz)
  m = f2b(r);
  l = f2b(r - b2f(m));
}
// 8 consecutive channels (two float4) -> 3-way bf16 split fragments
__device__ __forceinline__ void split8(float4 a, float4 b, bf16x8* S) {
  float v[8] = {a.x, a.y, a.z, a.w, b.x, b.y, b.z, b.w};
  #pragma unroll
  for (int e = 0; e < 8; ++e) {
    u16 h, m, l; split3(v[e], h, m, l);
    S[0][e] = (short)h; S[1][e] = (short)m; S[2][e] = (short)l;
  }
}
__device__ __forceinline__ bf16x8 tob8(float4 a, float4 b) {
  bf16x8 r;
  r[0] = (short)f2b(a.x); r[1] = (short)f2b(a.y); r[2] = (short)f2b(a.z); r[3] = (short)f2b(a.w);
  r[4] = (short)f2b(b.x); r[5] = (short)f2b(b.y); r[6] = (short)f2b(b.z); r[7] = (short)f2b(b.w);
  return r;
}
__device__ __forceinline__ float sigmoidf_(float x) { return 1.f / (1.f + expf(-x)); }

// ---------------- prep: probe k-map, split sigma w, pack color w ----------------
__global__ void __launch_bounds__(256)
prep_kernel(const float* __restrict__ ws0, const float* __restrict__ ws1,
            const float* __restrict__ ws2, const float* __restrict__ wc0,
            const float* __restrict__ wc1, const float* __restrict__ wc2,
            const float* __restrict__ wc3, u16* __restrict__ wb)
{
  __shared__ int P[32];
  __shared__ int Pinv[32];
  const int t = threadIdx.x;
  if (t < 64) {
    const int g = t >> 4;
    for (int tt = 0; tt < 32; ++tt) {
      bf16x8 A, B;
      #pragma unroll
      for (int e = 0; e < 8; ++e) {
        A[e] = (short)f2b((float)(g * 8 + e + 1));
        B[e] = (short)((g * 8 + e == tt) ? 0x3F80 : 0);
      }
      f32x4 c = {0.f, 0.f, 0.f, 0.f};
      c = __builtin_amdgcn_mfma_f32_16x16x32_bf16(A, B, c, 0, 0, 0);
      if (t == 0) P[tt] = (int)(c[0] + 0.5f) - 1;
    }
  }
  __syncthreads();
  if (t < 32) Pinv[t] = t;
  __syncthreads();
  if (t < 32) { int p = P[t]; if (p >= 0 && p < 32) Pinv[p] = t; }
  __syncthreads();

  for (int i = t; i < 2048; i += 256) {           // W0 splits [64][32]
    int o = i >> 5, k = i & 31, kt = Pinv[k];
    float v = ws0[kt * 64 + o];
    u16 h, m, l; split3(v, h, m, l);
    wb[SB_W0H + i] = h; wb[SB_W0M + i] = m; wb[SB_W0L + i] = l;
  }
  for (int i = t; i < 4096; i += 256) {           // W1 splits [64][64]
    int o = i >> 6, k = i & 63, kt = (k & 32) | Pinv[k & 31];
    float v = ws1[kt * 64 + o];
    u16 h, m, l; split3(v, h, m, l);
    wb[SB_W1H + i] = h; wb[SB_W1M + i] = m; wb[SB_W1L + i] = l;
  }
  for (int i = t; i < 1024; i += 256) {           // W2 plain bf16 [16][64]
    int o = i >> 6, s = i & 63, kt = (s & 32) | Pinv[s & 31];
    wb[WB_G + i] = f2b(ws2[kt * 16 + o]);
  }
  // color layer 0: cin slots 0..15 encd, 16 dead(sigma), 17..31 geo(1..15),
  // 32..47 app, 48..63 zero
  for (int i = t; i < 4096; i += 256) {
    int o = i >> 6, s = i & 63, kt = (s & 32) | Pinv[s & 31];
    float v = 0.f;
    if (kt < 16) v = wc0[kt * 64 + o];
    else if (kt >= 17 && kt <= 47) v = wc0[(kt - 1) * 64 + o];
    wb[WB_C0 + i] = f2b(v);
  }
  for (int i = t; i < 4096; i += 256) {
    int o = i >> 6, s = i & 63, kt = (s & 32) | Pinv[s & 31];
    wb[WB_C1 + i] = f2b(wc1[kt * 64 + o]);
  }
  for (int i = t; i < 4096; i += 256) {
    int o = i >> 6, s = i & 63, kt = (s & 32) | Pinv[s & 31];
    wb[WB_C2 + i] = f2b(wc2[kt * 64 + o]);
  }
  for (int i = t; i < 1024; i += 256) {
    int o = i >> 6, s = i & 63, kt = (s & 32) | Pinv[s & 31];
    wb[WB_C3 + i] = f2b(o < 3 ? wc3[kt * 3 + o] : 0.f);
  }
}

// ---------------- fused encode + per-n split-MFMA sigma + bf16 color ----------------
// 1 wave/block, 64 points. LDS/wave: EC 8KB (enc f32 rows, later color bf16 rows,
// aliased), H1/H2 4KB each (16 rows x 256B f32, per-n ping-pong). All rows
// XOR-swizzled by (row&7)<<4.
__global__ void __launch_bounds__(64, 2)
point_kernel(const float* __restrict__ rays, const float* __restrict__ tables,
             const u16* __restrict__ wb, const float* __restrict__ ws2,
             const float* __restrict__ app_table, u16* __restrict__ raw, ResArr RES)
{
  __shared__ char lds[16640];
  char* EC = lds;
  char* H1 = lds + 8192;
  char* H2 = lds + 12288;
  float* keepb = (float*)(lds + 16384);
  const int lane = threadIdx.x;
  const int pBase = blockIdx.x * 64;
  const int q = lane & 15, g = lane >> 4;
  const unsigned swzQ = (unsigned)((q & 7) << 4);
  const unsigned swzMy = (unsigned)((lane & 7) << 4);

  // ---------- phase 1: per-thread hash encode ----------
  const int ptG = pBase + lane;
  const int r = ptG >> 7, s = ptG & (NSAMP - 1);
  const float ox = rays[r * 7 + 0], oy = rays[r * 7 + 1], oz = rays[r * 7 + 2];
  const float dx = rays[r * 7 + 3], dy = rays[r * 7 + 4], dz = rays[r * 7 + 5];
  const int code = (int)rays[r * 7 + 6];
  const float z = 0.5f + (3.5f / 127.f) * (float)s;
  const float x = fmaf(dx, z, ox), y = fmaf(dy, z, oy), w = fmaf(dz, z, oz);
  const bool keep = (x >= -4.f && x <= 4.f && y >= -4.f && y <= 4.f &&
                     w >= -4.f && w <= 4.f);
  const float xc = fminf(fmaxf(x, -4.f), 4.f);
  const float yc = fminf(fmaxf(y, -4.f), 4.f);
  const float zc = fminf(fmaxf(w, -4.f), 4.f);

  float encp[32];
  #pragma unroll
  for (int l = 0; l < 16; ++l) {
    const float res = RES.r[l];
    const float sc = res * 0.125f;
    const float px = (xc + 4.f) * sc, py = (yc + 4.f) * sc, pz = (zc + 4.f) * sc;
    const float bx = floorf(px), by = floorf(py), bz = floorf(pz);
    const float fx = px - bx, fy = py - by, fz = pz - bz;
    const unsigned ix = (unsigned)bx, iy = (unsigned)by, iz = (unsigned)bz;
    const unsigned hx0 = ix, hx1 = ix + 1u;
    const unsigned hy0 = iy * 2654435761u, hy1 = (iy + 1u) * 2654435761u;
    const unsigned hz0 = iz * 805459861u,  hz1 = (iz + 1u) * 805459861u;
    const float wx0 = 1.f - fx, wy0 = 1.f - fy, wz0 = 1.f - fz;
    const float* tl = tables + (size_t)l * LVL_STRIDE;
    float f0 = 0.f, f1 = 0.f;
    #pragma unroll
    for (int c = 0; c < 8; ++c) {
      const unsigned cx = (c >> 2) & 1, cy = (c >> 1) & 1, cz = c & 1;
      const unsigned idx = ((cx ? hx1 : hx0) ^ (cy ? hy1 : hy0) ^ (cz ? hz1 : hz0)) & TBL_MASK;
      const float cw = (cx ? fx : wx0) * (cy ? fy : wy0) * (cz ? fz : wz0);
      const float2 e = *reinterpret_cast<const float2*>(tl + (size_t)idx * 2);
      f0 = fmaf(cw, e.x, f0);
      f1 = fmaf(cw, e.y, f1);
    }
    encp[2 * l] = f0;
    encp[2 * l + 1] = f1;
  }
  // dump enc f32 to own EC row (32 ch = 128 B)
  #pragma unroll
  for (int c = 0; c < 8; ++c) {
    float4 u = make_float4(encp[4 * c + 0], encp[4 * c + 1], encp[4 * c + 2], encp[4 * c + 3]);
    *(float4*)(EC + lane * 128 + (((unsigned)(c * 16)) ^ swzMy)) = u;
  }
  keepb[lane] = keep ? 1.f : 0.f;
  MEMBAR();

  // 6-product split-MFMA accumulate: pairs {hh,hm,hl,mh,mm,lh}
  auto six = [&](const u16* ph, const u16* pm, const u16* pl,
                 bf16x8 bh, bf16x8 bm, bf16x8 bl, f32x4 c) -> f32x4 {
    bf16x8 Ah = *(const bf16x8*)ph, Am = *(const bf16x8*)pm, Al = *(const bf16x8*)pl;
    c = __builtin_amdgcn_mfma_f32_16x16x32_bf16(Ah, bh, c, 0, 0, 0);
    c = __builtin_amdgcn_mfma_f32_16x16x32_bf16(Am, bh, c, 0, 0, 0);
    c = __builtin_amdgcn_mfma_f32_16x16x32_bf16(Al, bh, c, 0, 0, 0);
    c = __builtin_amdgcn_mfma_f32_16x16x32_bf16(Ah, bm, c, 0, 0, 0);
    c = __builtin_amdgcn_mfma_f32_16x16x32_bf16(Am, bm, c, 0, 0, 0);
    c = __builtin_amdgcn_mfma_f32_16x16x32_bf16(Ah, bl, c, 0, 0, 0);
    return c;
  };

  // ---------- phase 2: sigma MLP, per-n (16-point) pipeline ----------
  float sigv[4];
  #pragma unroll
  for (int n = 0; n < 4; ++n) {
    // L0: B = 3-split of enc rows n (f32, on-read)
    bf16x8 B0[3];
    {
      const char* p = EC + (n * 16 + q) * 128;
      float4 a = *(const float4*)(p + (((unsigned)(g * 32)) ^ swzQ));
      float4 b = *(const float4*)(p + (((unsigned)(g * 32 + 16)) ^ swzQ));
      split8(a, b, B0);
    }
    #pragma unroll
    for (int m = 0; m < 4; ++m) {
      const int row = (m * 16 + q) * 32 + g * 8;
      f32x4 c = {0.f, 0.f, 0.f, 0.f};
      c = six(wb + SB_W0H + row, wb + SB_W0M + row, wb + SB_W0L + row,
              B0[0], B0[1], B0[2], c);
      c[0] = fmaxf(c[0], 0.f); c[1] = fmaxf(c[1], 0.f);
      c[2] = fmaxf(c[2], 0.f); c[3] = fmaxf(c[3], 0.f);
      float4 st = make_float4(c[0], c[1], c[2], c[3]);
      *(float4*)(H1 + q * 256 + (((unsigned)(m * 64 + g * 16)) ^ swzQ)) = st;
    }
    MEMBAR();   // H1 writes -> H1 reads

    // L1: B = 3-split of h1 rows (f32, on-read), kc=0,1
    bf16x8 B1a[3], B1b[3];
    {
      const char* p = H1 + q * 256;
      float4 a0 = *(const float4*)(p + (((unsigned)(g * 32)) ^ swzQ));
      float4 b0 = *(const float4*)(p + (((unsigned)(g * 32 + 16)) ^ swzQ));
      split8(a0, b0, B1a);
      float4 a1 = *(const float4*)(p + (((unsigned)(128 + g * 32)) ^ swzQ));
      float4 b1 = *(const float4*)(p + (((unsigned)(128 + g * 32 + 16)) ^ swzQ));
      split8(a1, b1, B1b);
    }
    #pragma unroll
    for (int m = 0; m < 4; ++m) {
      const int r0 = (m * 16 + q) * 64 + g * 8;
      const int r1 = r0 + 32;
      f32x4 c = {0.f, 0.f, 0.f, 0.f};
      c = six(wb + SB_W1H + r0, wb + SB_W1M + r0, wb + SB_W1L + r0,
              B1a[0], B1a[1], B1a[2], c);
      c = six(wb + SB_W1H + r1, wb + SB_W1M + r1, wb + SB_W1L + r1,
              B1b[0], B1b[1], B1b[2], c);
      c[0] = fmaxf(c[0], 0.f); c[1] = fmaxf(c[1], 0.f);
      c[2] = fmaxf(c[2], 0.f); c[3] = fmaxf(c[3], 0.f);
      float4 st = make_float4(c[0], c[1], c[2], c[3]);
      *(float4*)(H2 + q * 256 + (((unsigned)(m * 64 + g * 16)) ^ swzQ)) = st;
    }
    MEMBAR();   // H2 writes -> H2 reads

    // L2 geo: plain bf16 MFMA (geo feeds sigmoid; bf16 suffices)
    {
      const char* p = H2 + q * 256;
      float4 a0 = *(const float4*)(p + (((unsigned)(g * 32)) ^ swzQ));
      float4 b0 = *(const float4*)(p + (((unsigned)(g * 32 + 16)) ^ swzQ));
      bf16x8 Bg0 = tob8(a0, b0);
      float4 a1 = *(const float4*)(p + (((unsigned)(128 + g * 32)) ^ swzQ));
      float4 b1 = *(const float4*)(p + (((unsigned)(128 + g * 32 + 16)) ^ swzQ));
      bf16x8 Bg1 = tob8(a1, b1);
      bf16x8 A0 = *(const bf16x8*)(wb + WB_G + q * 64 + g * 8);
      bf16x8 A1 = *(const bf16x8*)(wb + WB_G + q * 64 + 32 + g * 8);
      f32x4 cg = {0.f, 0.f, 0.f, 0.f};
      cg = __builtin_amdgcn_mfma_f32_16x16x32_bf16(A0, Bg0, cg, 0, 0, 0);
      cg = __builtin_amdgcn_mfma_f32_16x16x32_bf16(A1, Bg1, cg, 0, 0, 0);
      // geo (no relu) -> color slots 16+4g..19+4g of row n*16+q (slot16 weight=0)
      uint2 u; u.x = pack2(cg[0], cg[1]); u.y = pack2(cg[2], cg[3]);
      *(uint2*)(EC + (n * 16 + q) * 128 + (((unsigned)(32 + 8 * g)) ^ swzQ)) = u;
    }
    // sigma: exact f32 scalar dot  sp = sum_ch h2[ch] * ws2[ch][0]
    {
      float sp = 0.f;
      #pragma unroll
      for (int j4 = 0; j4 < 4; ++j4) {
        float4 h = *(const float4*)(H2 + q * 256 + (((unsigned)(g * 64 + j4 * 16)) ^ swzQ));
        const int ch = g * 16 + j4 * 4;
        sp = fmaf(h.x, ws2[(ch + 0) * 16], sp);
        sp = fmaf(h.y, ws2[(ch + 1) * 16], sp);
        sp = fmaf(h.z, ws2[(ch + 2) * 16], sp);
        sp = fmaf(h.w, ws2[(ch + 3) * 16], sp);
      }
      sp += __shfl_xor(sp, 16);
      sp += __shfl_xor(sp, 32);
      sigv[n] = sp * keepb[n * 16 + q];
    }
    MEMBAR();   // EC geo writes / H2 reads -> next n
  }

  // own row: encd slots 0..15, app 32..47, zeros 48..63
  {
    const float xx = dx * dx, yy = dy * dy, zz2 = dz * dz;
    const float xy = dx * dy, yz = dy * dz, xz = dx * dz;
    float e0 = 0.28209479177387814f;
    float e1 = -0.4886025119029199f * dy;
    float e2 = 0.4886025119029199f * dz;
    float e3 = -0.4886025119029199f * dx;
    float e4 = 1.0925484305920792f * xy;
    float e5 = -1.0925484305920792f * yz;
    float e6 = 0.31539156525252005f * (2.f * zz2 - xx - yy);
    float e7 = -1.0925484305920792f * xz;
    float e8 = 0.5462742152960396f * (xx - yy);
    float e9 = -0.5900435899266435f * dy * (3.f * xx - yy);
    float e10 = 2.890611442640554f * xy * dz;
    float e11 = -0.4570457994644658f * dy * (4.f * zz2 - xx - yy);
    float e12 = 0.3731763325901154f * dz * (2.f * zz2 - 3.f * xx - 3.f * yy);
    float e13 = -0.4570457994644658f * dx * (4.f * zz2 - xx - yy);
    float e14 = 1.445305721320277f * dz * (xx - yy);
    float e15 = -0.5900435899266435f * dx * (xx - 3.f * yy);
    uint4 u0; u0.x = pack2(e0, e1);  u0.y = pack2(e2, e3);  u0.z = pack2(e4, e5);  u0.w = pack2(e6, e7);
    uint4 u1; u1.x = pack2(e8, e9);  u1.y = pack2(e10, e11); u1.z = pack2(e12, e13); u1.w = pack2(e14, e15);
    *(uint4*)(EC + lane * 128 + (0u ^ swzMy)) = u0;
    *(uint4*)(EC + lane * 128 + (16u ^ swzMy)) = u1;
    const float4* ap = (const float4*)(app_table + (size_t)code * 16);
    float4 a0 = ap[0], a1 = ap[1], a2 = ap[2], a3 = ap[3];
    uint4 v0; v0.x = pack2(a0.x, a0.y); v0.y = pack2(a0.z, a0.w); v0.z = pack2(a1.x, a1.y); v0.w = pack2(a1.z, a1.w);
    uint4 v1; v1.x = pack2(a2.x, a2.y); v1.y = pack2(a2.z, a2.w); v1.z = pack2(a3.x, a3.y); v1.w = pack2(a3.z, a3.w);
    *(uint4*)(EC + lane * 128 + (64u ^ swzMy)) = v0;
    *(uint4*)(EC + lane * 128 + (80u ^ swzMy)) = v1;
    uint4 zv; zv.x = 0u; zv.y = 0u; zv.z = 0u; zv.w = 0u;
    *(uint4*)(EC + lane * 128 + (96u ^ swzMy)) = zv;
    *(uint4*)(EC + lane * 128 + (112u ^ swzMy)) = zv;
  }
  MEMBAR();

  // ---------- phase 3: color MFMA MLP (plain bf16, proven) ----------
  auto rdB = [&](int n, int kc) -> bf16x8 {
    return *(const bf16x8*)(EC + (n * 16 + q) * 128 + (((unsigned)(kc * 64 + g * 16)) ^ swzQ));
  };
  auto ldA = [&](const u16* Wp, int row, int kc) -> bf16x8 {
    return *(const bf16x8*)(Wp + row * 64 + kc * 32 + g * 8);
  };
  auto wrC = [&](int n, int slot0, f32x4 c) {
    c[0] = fmaxf(c[0], 0.f); c[1] = fmaxf(c[1], 0.f);
    c[2] = fmaxf(c[2], 0.f); c[3] = fmaxf(c[3], 0.f);
    uint2 u; u.x = pack2(c[0], c[1]); u.y = pack2(c[2], c[3]);
    *(uint2*)(EC + (n * 16 + q) * 128 + (((unsigned)(slot0 * 2)) ^ swzQ)) = u;
  };
  auto layer64 = [&](const u16* Wp) {
    bf16x8 A[4][2];
    #pragma unroll
    for (int m = 0; m < 4; ++m) {
      A[m][0] = ldA(Wp, m * 16 + q, 0);
      A[m][1] = ldA(Wp, m * 16 + q, 1);
    }
    #pragma unroll
    for (int n = 0; n < 4; ++n) {
      bf16x8 b0 = rdB(n, 0), b1 = rdB(n, 1);
      #pragma unroll
      for (int m = 0; m < 4; ++m) {
        f32x4 c = {0.f, 0.f, 0.f, 0.f};
        c = __builtin_amdgcn_mfma_f32_16x16x32_bf16(A[m][0], b0, c, 0, 0, 0);
        c = __builtin_amdgcn_mfma_f32_16x16x32_bf16(A[m][1], b1, c, 0, 0, 0);
        wrC(n, m * 16 + g * 4, c);
      }
    }
    MEMBAR();
  };

  layer64(wb + WB_C0);
  layer64(wb + WB_C1);
  layer64(wb + WB_C2);

  {
    const u16* Wp = wb + WB_C3;
    bf16x8 A0 = ldA(Wp, q, 0), A1 = ldA(Wp, q, 1);
    #pragma unroll
    for (int n = 0; n < 4; ++n) {
      bf16x8 b0 = rdB(n, 0), b1 = rdB(n, 1);
      f32x4 c = {0.f, 0.f, 0.f, 0.f};
      c = __builtin_amdgcn_mfma_f32_16x16x32_bf16(A0, b0, c, 0, 0, 0);
      c = __builtin_amdgcn_mfma_f32_16x16x32_bf16(A1, b1, c, 0, 0, 0);
      if (g == 0) {
        uint2 o; o.x = pack2(c[0], c[1]); o.y = pack2(c[2], sigv[n]);
        *(uint2*)(raw + (size_t)(pBase + n * 16 + q) * 4) = o;
      }
    }
  }
}

// ---------------- per-ray compositing ----------------
__global__ void __launch_bounds__(256)
render_kernel(const float* __restrict__ rays, const u16* __restrict__ raw,
              float* __restrict__ out)
{
  const int r = blockIdx.x * 256 + threadIdx.x;
  if (r >= NRAYS) return;
  const float dx = rays[r * 7 + 3], dy = rays[r * 7 + 4], dz = rays[r * 7 + 5];
  const float nrm = sqrtf(dx * dx + dy * dy + dz * dz);
  const float dstep = 3.5f / 127.f;
  const ushort4* rp = reinterpret_cast<const ushort4*>(raw) + (size_t)r * NSAMP;

  float T = 1.f, sumw = 0.f, sumwz = 0.f, cm0 = 0.f, cm1 = 0.f, cm2 = 0.f;
  for (int s = 0; s < NSAMP; ++s) {
    const ushort4 rw = rp[s];
    const float dist = ((s < NSAMP - 1) ? dstep : 1e10f) * nrm;
    const float sigv = fmaxf(b2f(rw.w), 0.f);
    const float alpha = 1.f - expf(-sigv * dist);
    const float wgt = alpha * T;
    T *= (1.f - alpha + 1e-10f);
    const float zv = 0.5f + dstep * (float)s;
    sumw += wgt;
    sumwz = fmaf(wgt, zv, sumwz);
    cm0 = fmaf(wgt, sigmoidf_(b2f(rw.x)), cm0);
    cm1 = fmaf(wgt, sigmoidf_(b2f(rw.y)), cm1);
    cm2 = fmaf(wgt, sigmoidf_(b2f(rw.z)), cm2);
  }

  float S1 = 0.f, S2 = 0.f, T2 = 1.f;
  for (int s = 0; s < NSAMP; ++s) {
    const ushort4 rw = rp[s];
    const float dist = ((s < NSAMP - 1) ? dstep : 1e10f) * nrm;
    const float sigv = fmaxf(b2f(rw.w), 0.f);
    const float alpha = 1.f - expf(-sigv * dist);
    const float wgt = alpha * T2;
    T2 *= (1.f - alpha + 1e-10f);
    const float qv = fmaxf(wgt, 1e-12f);
    S1 += qv;
    S2 = fmaf(qv, logf(qv), S2);
  }
  const float plast = fmaxf(1.f - sumw + 1e-6f, 1e-12f);
  S1 += plast;
  S2 = fmaf(plast, logf(plast), S2);
  const float ent = logf(S1) - S2 / S1;

  out[r * 3 + 0] = cm0;
  out[r * 3 + 1] = cm1;
  out[r * 3 + 2] = cm2;
  out[NRAYS * 3 + r] = sumwz;
  out[NRAYS * 4 + r] = ent;
}

extern "C" void kernel_launch(void* const* d_in, const int* in_sizes, int n_in,
                              void* d_out, int out_size, void* d_ws, size_t ws_size,
                              hipStream_t stream)
{
  const float* rays   = (const float*)d_in[0];
  const float* tables = (const float*)d_in[2];
  const float* ws0    = (const float*)d_in[3];
  const float* ws1    = (const float*)d_in[4];
  const float* ws2    = (const float*)d_in[5];
  const float* wc0    = (const float*)d_in[6];
  const float* wc1    = (const float*)d_in[7];
  const float* wc2    = (const float*)d_in[8];
  const float* wc3    = (const float*)d_in[9];
  const float* app    = (const float*)d_in[10];

  u16* wb  = (u16*)d_ws;
  u16* raw = (u16*)((char*)d_ws + RAW_OFF);
  float* out = (float*)d_out;

  ResArr RES;
  const double b = exp((log(512.0) - log(16.0)) / 15.0);
  for (int l = 0; l < 16; ++l) RES.r[l] = (float)floor(16.0 * pow(b, (double)l));

  hipLaunchKernelGGL(prep_kernel, dim3(1), dim3(256), 0, stream,
                     ws0, ws1, ws2, wc0, wc1, wc2, wc3, wb);
  hipLaunchKernelGGL(point_kernel, dim3(NPTS / 64), dim3(64), 0, stream,
                     rays, tables, wb, ws2, app, raw, RES);
  hipLaunchKernelGGL(render_kernel, dim3(16), dim3(256), 0, stream,
                     rays, raw, out);
}

// Round 8
// 322.152 us; speedup vs baseline: 1.7861x; 1.0358x over previous
//
#include <hip/hip_runtime.h>
#include <math.h>

typedef unsigned short u16;
typedef short bf16x8 __attribute__((ext_vector_type(8)));
typedef float f32x4 __attribute__((ext_vector_type(4)));

#define NRAYS 4096
#define NSAMP 128
#define NPTS (NRAYS * NSAMP)
#define TBL_MASK 0x7FFFFu
#define LVL_STRIDE (524288 * 2)

// d_ws u16-element offsets
#define W0H  0        // [64][32] h
#define W0M  2048     // [64][32] m
#define W1H  4096     // [64][64] h
#define W1M  8192     // [64][64] m
#define WBG  12288    // [16][64] plain bf16 W2 (geo)
#define WBC0 13312    // [64][64] remapped rows
#define WBC1 17408
#define WBC2 21504
#define WBC3 25600    // [16][64]
#define W2C0_OFF 57344   // byte offset: f32[64] = ws2 column 0
#define RAW_OFF 131072   // byte offset of raw (bf16x4/point = 4 MB)

#define MEMBAR() asm volatile("" ::: "memory")

struct ResArr { float r[16]; };

__device__ __forceinline__ u16 f2b(float f) {   // RNE f32->bf16
  unsigned u = __float_as_uint(f);
  unsigned r = u + 0x7FFFu + ((u >> 16) & 1u);
  return (u16)(r >> 16);
}
__device__ __forceinline__ unsigned pack2(float lo, float hi) {
  return (unsigned)f2b(lo) | ((unsigned)f2b(hi) << 16);
}
__device__ __forceinline__ float b2f(u16 u) {
  return __uint_as_float(((unsigned)u) << 16);
}
// 8 channels (two float4) -> 2-way split fragments (h, m)
__device__ __forceinline__ void split2_8(float4 a, float4 b, bf16x8& H, bf16x8& M) {
  float v[8] = {a.x, a.y, a.z, a.w, b.x, b.y, b.z, b.w};
  #pragma unroll
  for (int e = 0; e < 8; ++e) {
    u16 h = f2b(v[e]);
    H[e] = (short)h;
    M[e] = (short)f2b(v[e] - b2f(h));    // exact residual (Sterbenz)
  }
}
__device__ __forceinline__ bf16x8 tob8(float4 a, float4 b) {
  bf16x8 r;
  r[0] = (short)f2b(a.x); r[1] = (short)f2b(a.y); r[2] = (short)f2b(a.z); r[3] = (short)f2b(a.w);
  r[4] = (short)f2b(b.x); r[5] = (short)f2b(b.y); r[6] = (short)f2b(b.z); r[7] = (short)f2b(b.w);
  return r;
}
__device__ __forceinline__ float sigmoidf_(float x) { return 1.f / (1.f + expf(-x)); }

// ---------------- prep: probe k-map, 2-way-split sigma w, pack color w ----------------
__global__ void __launch_bounds__(256)
prep_kernel(const float* __restrict__ ws0, const float* __restrict__ ws1,
            const float* __restrict__ ws2, const float* __restrict__ wc0,
            const float* __restrict__ wc1, const float* __restrict__ wc2,
            const float* __restrict__ wc3, u16* __restrict__ wb,
            float* __restrict__ w2c0)
{
  __shared__ int P[32];
  __shared__ int Pinv[32];
  const int t = threadIdx.x;
  if (t < 64) {
    const int g = t >> 4;
    for (int tt = 0; tt < 32; ++tt) {
      bf16x8 A, B;
      #pragma unroll
      for (int e = 0; e < 8; ++e) {
        A[e] = (short)f2b((float)(g * 8 + e + 1));
        B[e] = (short)((g * 8 + e == tt) ? 0x3F80 : 0);
      }
      f32x4 c = {0.f, 0.f, 0.f, 0.f};
      c = __builtin_amdgcn_mfma_f32_16x16x32_bf16(A, B, c, 0, 0, 0);
      if (t == 0) P[tt] = (int)(c[0] + 0.5f) - 1;
    }
  }
  __syncthreads();
  if (t < 32) Pinv[t] = t;
  __syncthreads();
  if (t < 32) { int p = P[t]; if (p >= 0 && p < 32) Pinv[p] = t; }
  __syncthreads();

  const int gt = blockIdx.x * 256 + t;
  const int GS = 8 * 256;
  for (int i = gt; i < 2048; i += GS) {          // W0 [64][32] h/m
    int o = i >> 5, k = i & 31, kt = Pinv[k];
    float v = ws0[kt * 64 + o];
    u16 h = f2b(v);
    wb[W0H + i] = h; wb[W0M + i] = f2b(v - b2f(h));
  }
  for (int i = gt; i < 4096; i += GS) {          // W1 [64][64] h/m
    int o = i >> 6, k = i & 63, kt = (k & 32) | Pinv[k & 31];
    float v = ws1[kt * 64 + o];
    u16 h = f2b(v);
    wb[W1H + i] = h; wb[W1M + i] = f2b(v - b2f(h));
  }
  for (int i = gt; i < 1024; i += GS) {          // W2 geo plain bf16 [16][64]
    int o = i >> 6, s = i & 63, kt = (s & 32) | Pinv[s & 31];
    wb[WBG + i] = f2b(ws2[kt * 16 + o]);
  }
  for (int i = gt; i < 64; i += GS) w2c0[i] = ws2[i * 16];   // sigma col f32
  // color layer 0: cin slots 0..15 encd, 16 dead(sigma), 17..31 geo(1..15),
  // 32..47 app, 48..63 zero
  for (int i = gt; i < 4096; i += GS) {
    int o = i >> 6, s = i & 63, kt = (s & 32) | Pinv[s & 31];
    float v = 0.f;
    if (kt < 16) v = wc0[kt * 64 + o];
    else if (kt >= 17 && kt <= 47) v = wc0[(kt - 1) * 64 + o];
    wb[WBC0 + i] = f2b(v);
  }
  for (int i = gt; i < 4096; i += GS) {
    int o = i >> 6, s = i & 63, kt = (s & 32) | Pinv[s & 31];
    wb[WBC1 + i] = f2b(wc1[kt * 64 + o]);
  }
  for (int i = gt; i < 4096; i += GS) {
    int o = i >> 6, s = i & 63, kt = (s & 32) | Pinv[s & 31];
    wb[WBC2 + i] = f2b(wc2[kt * 64 + o]);
  }
  for (int i = gt; i < 1024; i += GS) {
    int o = i >> 6, s = i & 63, kt = (s & 32) | Pinv[s & 31];
    wb[WBC3 + i] = f2b(o < 3 ? wc3[kt * 3 + o] : 0.f);
  }
}

// ---------------- fused encode + half-tile split-MFMA sigma + bf16 color ----------------
// 1 wave/block. LDS: EC 8KB (enc f32 rows -> color bf16 rows, aliased) +
// HB 2KB (16 rows x 128B, half-tile ping-pong for h1/h2). 10240 B total ->
// 16 blocks/CU; launch_bounds(64,4) caps VGPR<=128 -> 16 waves/CU.
__global__ void __launch_bounds__(64, 4)
point_kernel(const float* __restrict__ rays, const float* __restrict__ tables,
             const u16* __restrict__ wb, const float* __restrict__ w2c0,
             const float* __restrict__ app_table, u16* __restrict__ raw, ResArr RES)
{
  __shared__ char lds[10240];
  char* EC = lds;
  char* HB = lds + 8192;
  const int lane = threadIdx.x;
  const int pBase = blockIdx.x * 64;
  const int q = lane & 15, g = lane >> 4;
  const unsigned swzQ = (unsigned)((q & 7) << 4);
  const unsigned swzMy = (unsigned)((lane & 7) << 4);

  // ---------- phase 1: per-thread hash encode ----------
  const int ptG = pBase + lane;
  const int r = ptG >> 7, s = ptG & (NSAMP - 1);
  const float ox = rays[r * 7 + 0], oy = rays[r * 7 + 1], oz = rays[r * 7 + 2];
  const float dx = rays[r * 7 + 3], dy = rays[r * 7 + 4], dz = rays[r * 7 + 5];
  const int code = (int)rays[r * 7 + 6];
  const float z = 0.5f + (3.5f / 127.f) * (float)s;
  const float x = fmaf(dx, z, ox), y = fmaf(dy, z, oy), w = fmaf(dz, z, oz);
  const bool keep = (x >= -4.f && x <= 4.f && y >= -4.f && y <= 4.f &&
                     w >= -4.f && w <= 4.f);
  const float keepf = keep ? 1.f : 0.f;
  const float xc = fminf(fmaxf(x, -4.f), 4.f);
  const float yc = fminf(fmaxf(y, -4.f), 4.f);
  const float zc = fminf(fmaxf(w, -4.f), 4.f);

  float encp[32];
  #pragma unroll
  for (int l = 0; l < 16; ++l) {
    const float res = RES.r[l];
    const float sc = res * 0.125f;
    const float px = (xc + 4.f) * sc, py = (yc + 4.f) * sc, pz = (zc + 4.f) * sc;
    const float bx = floorf(px), by = floorf(py), bz = floorf(pz);
    const float fx = px - bx, fy = py - by, fz = pz - bz;
    const unsigned ix = (unsigned)bx, iy = (unsigned)by, iz = (unsigned)bz;
    const unsigned hx0 = ix, hx1 = ix + 1u;
    const unsigned hy0 = iy * 2654435761u, hy1 = (iy + 1u) * 2654435761u;
    const unsigned hz0 = iz * 805459861u,  hz1 = (iz + 1u) * 805459861u;
    const float wx0 = 1.f - fx, wy0 = 1.f - fy, wz0 = 1.f - fz;
    const float* tl = tables + (size_t)l * LVL_STRIDE;
    float f0 = 0.f, f1 = 0.f;
    #pragma unroll
    for (int c = 0; c < 8; ++c) {
      const unsigned cx = (c >> 2) & 1, cy = (c >> 1) & 1, cz = c & 1;
      const unsigned idx = ((cx ? hx1 : hx0) ^ (cy ? hy1 : hy0) ^ (cz ? hz1 : hz0)) & TBL_MASK;
      const float cw = (cx ? fx : wx0) * (cy ? fy : wy0) * (cz ? fz : wz0);
      const float2 e = *reinterpret_cast<const float2*>(tl + (size_t)idx * 2);
      f0 = fmaf(cw, e.x, f0);
      f1 = fmaf(cw, e.y, f1);
    }
    encp[2 * l] = f0;
    encp[2 * l + 1] = f1;
  }
  #pragma unroll
  for (int c = 0; c < 8; ++c) {
    float4 u = make_float4(encp[4 * c + 0], encp[4 * c + 1], encp[4 * c + 2], encp[4 * c + 3]);
    *(float4*)(EC + lane * 128 + (((unsigned)(c * 16)) ^ swzMy)) = u;
  }
  MEMBAR();

  // 4-product 2-way-split accumulate (hh, mh, hm, mm)
  auto four = [&](const u16* pH, const u16* pM, bf16x8 bh, bf16x8 bm, f32x4 c) -> f32x4 {
    bf16x8 Ah = *(const bf16x8*)pH, Am = *(const bf16x8*)pM;
    c = __builtin_amdgcn_mfma_f32_16x16x32_bf16(Ah, bh, c, 0, 0, 0);
    c = __builtin_amdgcn_mfma_f32_16x16x32_bf16(Am, bh, c, 0, 0, 0);
    c = __builtin_amdgcn_mfma_f32_16x16x32_bf16(Ah, bm, c, 0, 0, 0);
    c = __builtin_amdgcn_mfma_f32_16x16x32_bf16(Am, bm, c, 0, 0, 0);
    return c;
  };
  // store C half-tile (lane q,g holds ch (m&1)*16+g*4..+3 of point-col q) into HB
  auto stH = [&](int mh, f32x4 c, bool relu) {
    if (relu) {
      c[0] = fmaxf(c[0], 0.f); c[1] = fmaxf(c[1], 0.f);
      c[2] = fmaxf(c[2], 0.f); c[3] = fmaxf(c[3], 0.f);
    }
    *(float4*)(HB + q * 128 + (((unsigned)(mh * 64 + g * 16)) ^ swzQ)) =
        make_float4(c[0], c[1], c[2], c[3]);
  };

  // ---------- phase 2: sigma MLP, per-n, half-tile ping-pong in HB ----------
  float sigv[4];
  #pragma unroll
  for (int n = 0; n < 4; ++n) {
    // B0: 2-way split of enc row (n*16+q)
    bf16x8 B0h, B0m;
    {
      const char* p = EC + (n * 16 + q) * 128;
      float4 a = *(const float4*)(p + (((unsigned)(g * 32)) ^ swzQ));
      float4 b = *(const float4*)(p + (((unsigned)(g * 32 + 16)) ^ swzQ));
      split2_8(a, b, B0h, B0m);
    }
    f32x4 acc1[4];
    #pragma unroll
    for (int m = 0; m < 4; ++m) acc1[m] = f32x4{0.f, 0.f, 0.f, 0.f};

    // L0 half a (h1 ch 0..31) -> HB
    #pragma unroll
    for (int m = 0; m < 2; ++m) {
      const int row = (m * 16 + q) * 32 + g * 8;
      f32x4 c = {0.f, 0.f, 0.f, 0.f};
      c = four(wb + W0H + row, wb + W0M + row, B0h, B0m, c);
      stH(m, c, true);
    }
    MEMBAR();
    // L1 kc=0
    {
      float4 a = *(const float4*)(HB + q * 128 + (((unsigned)(g * 32)) ^ swzQ));
      float4 b = *(const float4*)(HB + q * 128 + (((unsigned)(g * 32 + 16)) ^ swzQ));
      bf16x8 Bh, Bm; split2_8(a, b, Bh, Bm);
      #pragma unroll
      for (int m = 0; m < 4; ++m) {
        const int row = (m * 16 + q) * 64 + g * 8;
        acc1[m] = four(wb + W1H + row, wb + W1M + row, Bh, Bm, acc1[m]);
      }
    }
    MEMBAR();
    // L0 half b (h1 ch 32..63) -> HB
    #pragma unroll
    for (int m = 2; m < 4; ++m) {
      const int row = (m * 16 + q) * 32 + g * 8;
      f32x4 c = {0.f, 0.f, 0.f, 0.f};
      c = four(wb + W0H + row, wb + W0M + row, B0h, B0m, c);
      stH(m & 1, c, true);
    }
    MEMBAR();
    // L1 kc=1
    {
      float4 a = *(const float4*)(HB + q * 128 + (((unsigned)(g * 32)) ^ swzQ));
      float4 b = *(const float4*)(HB + q * 128 + (((unsigned)(g * 32 + 16)) ^ swzQ));
      bf16x8 Bh, Bm; split2_8(a, b, Bh, Bm);
      #pragma unroll
      for (int m = 0; m < 4; ++m) {
        const int row = (m * 16 + q) * 64 + 32 + g * 8;
        acc1[m] = four(wb + W1H + row, wb + W1M + row, Bh, Bm, acc1[m]);
      }
    }
    #pragma unroll
    for (int m = 0; m < 4; ++m) {
      acc1[m][0] = fmaxf(acc1[m][0], 0.f); acc1[m][1] = fmaxf(acc1[m][1], 0.f);
      acc1[m][2] = fmaxf(acc1[m][2], 0.f); acc1[m][3] = fmaxf(acc1[m][3], 0.f);
    }
    MEMBAR();
    // L2: geo (plain bf16) + sigma dot (f32), via the same half-tile HB
    f32x4 gc = {0.f, 0.f, 0.f, 0.f};
    float sp = 0.f;
    stH(0, acc1[0], false); stH(1, acc1[1], false);
    MEMBAR();
    {
      float4 a = *(const float4*)(HB + q * 128 + (((unsigned)(g * 32)) ^ swzQ));
      float4 b = *(const float4*)(HB + q * 128 + (((unsigned)(g * 32 + 16)) ^ swzQ));
      bf16x8 Bg = tob8(a, b);
      gc = __builtin_amdgcn_mfma_f32_16x16x32_bf16(
          *(const bf16x8*)(wb + WBG + q * 64 + g * 8), Bg, gc, 0, 0, 0);
      float4 wa = *(const float4*)(w2c0 + g * 8);
      float4 wb4 = *(const float4*)(w2c0 + g * 8 + 4);
      sp = fmaf(a.x, wa.x, sp); sp = fmaf(a.y, wa.y, sp);
      sp = fmaf(a.z, wa.z, sp); sp = fmaf(a.w, wa.w, sp);
      sp = fmaf(b.x, wb4.x, sp); sp = fmaf(b.y, wb4.y, sp);
      sp = fmaf(b.z, wb4.z, sp); sp = fmaf(b.w, wb4.w, sp);
    }
    MEMBAR();
    stH(0, acc1[2], false); stH(1, acc1[3], false);
    MEMBAR();
    {
      float4 a = *(const float4*)(HB + q * 128 + (((unsigned)(g * 32)) ^ swzQ));
      float4 b = *(const float4*)(HB + q * 128 + (((unsigned)(g * 32 + 16)) ^ swzQ));
      bf16x8 Bg = tob8(a, b);
      gc = __builtin_amdgcn_mfma_f32_16x16x32_bf16(
          *(const bf16x8*)(wb + WBG + q * 64 + 32 + g * 8), Bg, gc, 0, 0, 0);
      float4 wa = *(const float4*)(w2c0 + 32 + g * 8);
      float4 wb4 = *(const float4*)(w2c0 + 32 + g * 8 + 4);
      sp = fmaf(a.x, wa.x, sp); sp = fmaf(a.y, wa.y, sp);
      sp = fmaf(a.z, wa.z, sp); sp = fmaf(a.w, wa.w, sp);
      sp = fmaf(b.x, wb4.x, sp); sp = fmaf(b.y, wb4.y, sp);
      sp = fmaf(b.z, wb4.z, sp); sp = fmaf(b.w, wb4.w, sp);
    }
    // geo (no relu) -> color slots 16+4g..19+4g of row n*16+q (slot16 weight=0)
    {
      uint2 u; u.x = pack2(gc[0], gc[1]); u.y = pack2(gc[2], gc[3]);
      *(uint2*)(EC + (n * 16 + q) * 128 + (((unsigned)(32 + 8 * g)) ^ swzQ)) = u;
    }
    sp += __shfl_xor(sp, 16);
    sp += __shfl_xor(sp, 32);
    sigv[n] = sp * __shfl(keepf, n * 16 + q);
    MEMBAR();
  }

  // own row: encd slots 0..15, app 32..47, zeros 48..63
  {
    const float xx = dx * dx, yy = dy * dy, zz2 = dz * dz;
    const float xy = dx * dy, yz = dy * dz, xz = dx * dz;
    float e0 = 0.28209479177387814f;
    float e1 = -0.4886025119029199f * dy;
    float e2 = 0.4886025119029199f * dz;
    float e3 = -0.4886025119029199f * dx;
    float e4 = 1.0925484305920792f * xy;
    float e5 = -1.0925484305920792f * yz;
    float e6 = 0.31539156525252005f * (2.f * zz2 - xx - yy);
    float e7 = -1.0925484305920792f * xz;
    float e8 = 0.5462742152960396f * (xx - yy);
    float e9 = -0.5900435899266435f * dy * (3.f * xx - yy);
    float e10 = 2.890611442640554f * xy * dz;
    float e11 = -0.4570457994644658f * dy * (4.f * zz2 - xx - yy);
    float e12 = 0.3731763325901154f * dz * (2.f * zz2 - 3.f * xx - 3.f * yy);
    float e13 = -0.4570457994644658f * dx * (4.f * zz2 - xx - yy);
    float e14 = 1.445305721320277f * dz * (xx - yy);
    float e15 = -0.5900435899266435f * dx * (xx - 3.f * yy);
    uint4 u0; u0.x = pack2(e0, e1);  u0.y = pack2(e2, e3);  u0.z = pack2(e4, e5);  u0.w = pack2(e6, e7);
    uint4 u1; u1.x = pack2(e8, e9);  u1.y = pack2(e10, e11); u1.z = pack2(e12, e13); u1.w = pack2(e14, e15);
    *(uint4*)(EC + lane * 128 + (0u ^ swzMy)) = u0;
    *(uint4*)(EC + lane * 128 + (16u ^ swzMy)) = u1;
    const float4* ap = (const float4*)(app_table + (size_t)code * 16);
    float4 a0 = ap[0], a1 = ap[1], a2 = ap[2], a3 = ap[3];
    uint4 v0; v0.x = pack2(a0.x, a0.y); v0.y = pack2(a0.z, a0.w); v0.z = pack2(a1.x, a1.y); v0.w = pack2(a1.z, a1.w);
    uint4 v1; v1.x = pack2(a2.x, a2.y); v1.y = pack2(a2.z, a2.w); v1.z = pack2(a3.x, a3.y); v1.w = pack2(a3.z, a3.w);
    *(uint4*)(EC + lane * 128 + (64u ^ swzMy)) = v0;
    *(uint4*)(EC + lane * 128 + (80u ^ swzMy)) = v1;
    uint4 zv; zv.x = 0u; zv.y = 0u; zv.z = 0u; zv.w = 0u;
    *(uint4*)(EC + lane * 128 + (96u ^ swzMy)) = zv;
    *(uint4*)(EC + lane * 128 + (112u ^ swzMy)) = zv;
  }
  MEMBAR();

  // ---------- phase 3: color MFMA MLP (plain bf16, proven) ----------
  auto rdB = [&](int n, int kc) -> bf16x8 {
    return *(const bf16x8*)(EC + (n * 16 + q) * 128 + (((unsigned)(kc * 64 + g * 16)) ^ swzQ));
  };
  auto ldA = [&](const u16* Wp, int row, int kc) -> bf16x8 {
    return *(const bf16x8*)(Wp + row * 64 + kc * 32 + g * 8);
  };
  auto wrC = [&](int n, int slot0, f32x4 c) {
    c[0] = fmaxf(c[0], 0.f); c[1] = fmaxf(c[1], 0.f);
    c[2] = fmaxf(c[2], 0.f); c[3] = fmaxf(c[3], 0.f);
    uint2 u; u.x = pack2(c[0], c[1]); u.y = pack2(c[2], c[3]);
    *(uint2*)(EC + (n * 16 + q) * 128 + (((unsigned)(slot0 * 2)) ^ swzQ)) = u;
  };
  auto layer64 = [&](const u16* Wp) {
    bf16x8 A[4][2];
    #pragma unroll
    for (int m = 0; m < 4; ++m) {
      A[m][0] = ldA(Wp, m * 16 + q, 0);
      A[m][1] = ldA(Wp, m * 16 + q, 1);
    }
    #pragma unroll
    for (int n = 0; n < 4; ++n) {
      bf16x8 b0 = rdB(n, 0), b1 = rdB(n, 1);
      #pragma unroll
      for (int m = 0; m < 4; ++m) {
        f32x4 c = {0.f, 0.f, 0.f, 0.f};
        c = __builtin_amdgcn_mfma_f32_16x16x32_bf16(A[m][0], b0, c, 0, 0, 0);
        c = __builtin_amdgcn_mfma_f32_16x16x32_bf16(A[m][1], b1, c, 0, 0, 0);
        wrC(n, m * 16 + g * 4, c);
      }
    }
    MEMBAR();
  };

  layer64(wb + WBC0);
  layer64(wb + WBC1);
  layer64(wb + WBC2);

  {
    const u16* Wp = wb + WBC3;
    bf16x8 A0 = ldA(Wp, q, 0), A1 = ldA(Wp, q, 1);
    #pragma unroll
    for (int n = 0; n < 4; ++n) {
      bf16x8 b0 = rdB(n, 0), b1 = rdB(n, 1);
      f32x4 c = {0.f, 0.f, 0.f, 0.f};
      c = __builtin_amdgcn_mfma_f32_16x16x32_bf16(A0, b0, c, 0, 0, 0);
      c = __builtin_amdgcn_mfma_f32_16x16x32_bf16(A1, b1, c, 0, 0, 0);
      if (g == 0) {
        uint2 o; o.x = pack2(c[0], c[1]); o.y = pack2(c[2], sigv[n]);
        *(uint2*)(raw + (size_t)(pBase + n * 16 + q) * 4) = o;
      }
    }
  }
}

// ---------------- per-ray compositing (single merged pass) ----------------
__global__ void __launch_bounds__(64)
render_kernel(const float* __restrict__ rays, const u16* __restrict__ raw,
              float* __restrict__ out)
{
  const int r = blockIdx.x * 64 + threadIdx.x;
  if (r >= NRAYS) return;
  const float dx = rays[r * 7 + 3], dy = rays[r * 7 + 4], dz = rays[r * 7 + 5];
  const float nrm = sqrtf(dx * dx + dy * dy + dz * dz);
  const float dstep = 3.5f / 127.f;
  const ushort4* rp = reinterpret_cast<const ushort4*>(raw) + (size_t)r * NSAMP;

  float T = 1.f, sumw = 0.f, sumwz = 0.f, cm0 = 0.f, cm1 = 0.f, cm2 = 0.f;
  float S1 = 0.f, S2 = 0.f;
  for (int s = 0; s < NSAMP; ++s) {
    const ushort4 rw = rp[s];
    const float dist = ((s < NSAMP - 1) ? dstep : 1e10f) * nrm;
    const float sigv = fmaxf(b2f(rw.w), 0.f);
    const float alpha = 1.f - expf(-sigv * dist);
    const float wgt = alpha * T;
    T *= (1.f - alpha + 1e-10f);
    const float zv = 0.5f + dstep * (float)s;
    sumw += wgt;
    sumwz = fmaf(wgt, zv, sumwz);
    cm0 = fmaf(wgt, sigmoidf_(b2f(rw.x)), cm0);
    cm1 = fmaf(wgt, sigmoidf_(b2f(rw.y)), cm1);
    cm2 = fmaf(wgt, sigmoidf_(b2f(rw.z)), cm2);
    const float qv = fmaxf(wgt, 1e-12f);
    S1 += qv;
    S2 = fmaf(qv, logf(qv), S2);
  }
  const float plast = fmaxf(1.f - sumw + 1e-6f, 1e-12f);
  S1 += plast;
  S2 = fmaf(plast, logf(plast), S2);
  const float ent = logf(S1) - S2 / S1;

  out[r * 3 + 0] = cm0;
  out[r * 3 + 1] = cm1;
  out[r * 3 + 2] = cm2;
  out[NRAYS * 3 + r] = sumwz;
  out[NRAYS * 4 + r] = ent;
}

extern "C" void kernel_launch(void* const* d_in, const int* in_sizes, int n_in,
                              void* d_out, int out_size, void* d_ws, size_t ws_size,
                              hipStream_t stream)
{
  const float* rays   = (const float*)d_in[0];
  const float* tables = (const float*)d_in[2];
  const float* ws0    = (const float*)d_in[3];
  const float* ws1    = (const float*)d_in[4];
  const float* ws2    = (const float*)d_in[5];
  const float* wc0    = (const float*)d_in[6];
  const float* wc1    = (const float*)d_in[7];
  const float* wc2    = (const float*)d_in[8];
  const float* wc3    = (const float*)d_in[9];
  const float* app    = (const float*)d_in[10];

  u16* wb    = (u16*)d_ws;
  float* w2c0 = (float*)((char*)d_ws + W2C0_OFF);
  u16* raw   = (u16*)((char*)d_ws + RAW_OFF);
  float* out = (float*)d_out;

  ResArr RES;
  const double b = exp((log(512.0) - log(16.0)) / 15.0);
  for (int l = 0; l < 16; ++l) RES.r[l] = (float)floor(16.0 * pow(b, (double)l));

  hipLaunchKernelGGL(prep_kernel, dim3(8), dim3(256), 0, stream,
                     ws0, ws1, ws2, wc0, wc1, wc2, wc3, wb, w2c0);
  hipLaunchKernelGGL(point_kernel, dim3(NPTS / 64), dim3(64), 0, stream,
                     rays, tables, wb, w2c0, app, raw, RES);
  hipLaunchKernelGGL(render_kernel, dim3(NRAYS / 64), dim3(64), 0, stream,
                     rays, raw, out);
}

// Round 9
// 321.581 us; speedup vs baseline: 1.7893x; 1.0018x over previous
//
#include <hip/hip_runtime.h>
#include <math.h>

typedef unsigned short u16;
typedef short bf16x8 __attribute__((ext_vector_type(8)));
typedef float f32x4 __attribute__((ext_vector_type(4)));

#define NRAYS 4096
#define NSAMP 128
#define NPTS (NRAYS * NSAMP)
#define TBL_MASK 0x7FFFFu
#define LVL_STRIDE (524288 * 2)

// d_ws u16-element offsets
#define W0H  0        // [64][32] h
#define W0M  2048     // [64][32] m
#define W1H  4096     // [64][64] h
#define W1M  8192     // [64][64] m
#define WBG  12288    // [16][64] plain bf16 W2 (geo)
#define WBC0 13312    // [64][64] remapped rows
#define WBC1 17408
#define WBC2 21504
#define WBC3 25600    // [16][64]
#define W2C0_OFF 57344   // byte offset: f32[64] = ws2 column 0
#define RAW_OFF 131072   // byte offset of raw (bf16x4/point = 4 MB)

#define MEMBAR() asm volatile("" ::: "memory")

struct ResArr { float r[16]; };

__device__ __forceinline__ u16 f2b(float f) {   // RNE f32->bf16
  unsigned u = __float_as_uint(f);
  unsigned r = u + 0x7FFFu + ((u >> 16) & 1u);
  return (u16)(r >> 16);
}
__device__ __forceinline__ unsigned pack2(float lo, float hi) {
  return (unsigned)f2b(lo) | ((unsigned)f2b(hi) << 16);
}
__device__ __forceinline__ float b2f(u16 u) {
  return __uint_as_float(((unsigned)u) << 16);
}
// 8 channels (two float4) -> 2-way split fragments (h, m)
__device__ __forceinline__ void split2_8(float4 a, float4 b, bf16x8& H, bf16x8& M) {
  float v[8] = {a.x, a.y, a.z, a.w, b.x, b.y, b.z, b.w};
  #pragma unroll
  for (int e = 0; e < 8; ++e) {
    u16 h = f2b(v[e]);
    H[e] = (short)h;
    M[e] = (short)f2b(v[e] - b2f(h));    // exact residual (Sterbenz)
  }
}
__device__ __forceinline__ bf16x8 tob8(float4 a, float4 b) {
  bf16x8 r;
  r[0] = (short)f2b(a.x); r[1] = (short)f2b(a.y); r[2] = (short)f2b(a.z); r[3] = (short)f2b(a.w);
  r[4] = (short)f2b(b.x); r[5] = (short)f2b(b.y); r[6] = (short)f2b(b.z); r[7] = (short)f2b(b.w);
  return r;
}
__device__ __forceinline__ float sigmoidf_(float x) { return 1.f / (1.f + expf(-x)); }

// ---------------- prep: probe k-map, 2-way-split sigma w, pack color w ----------------
__global__ void __launch_bounds__(256)
prep_kernel(const float* __restrict__ ws0, const float* __restrict__ ws1,
            const float* __restrict__ ws2, const float* __restrict__ wc0,
            const float* __restrict__ wc1, const float* __restrict__ wc2,
            const float* __restrict__ wc3, u16* __restrict__ wb,
            float* __restrict__ w2c0)
{
  __shared__ int P[32];
  __shared__ int Pinv[32];
  const int t = threadIdx.x;
  if (t < 64) {
    const int g = t >> 4;
    for (int tt = 0; tt < 32; ++tt) {
      bf16x8 A, B;
      #pragma unroll
      for (int e = 0; e < 8; ++e) {
        A[e] = (short)f2b((float)(g * 8 + e + 1));
        B[e] = (short)((g * 8 + e == tt) ? 0x3F80 : 0);
      }
      f32x4 c = {0.f, 0.f, 0.f, 0.f};
      c = __builtin_amdgcn_mfma_f32_16x16x32_bf16(A, B, c, 0, 0, 0);
      if (t == 0) P[tt] = (int)(c[0] + 0.5f) - 1;
    }
  }
  __syncthreads();
  if (t < 32) Pinv[t] = t;
  __syncthreads();
  if (t < 32) { int p = P[t]; if (p >= 0 && p < 32) Pinv[p] = t; }
  __syncthreads();

  const int gt = blockIdx.x * 256 + t;
  const int GS = 8 * 256;
  for (int i = gt; i < 2048; i += GS) {          // W0 [64][32] h/m
    int o = i >> 5, k = i & 31, kt = Pinv[k];
    float v = ws0[kt * 64 + o];
    u16 h = f2b(v);
    wb[W0H + i] = h; wb[W0M + i] = f2b(v - b2f(h));
  }
  for (int i = gt; i < 4096; i += GS) {          // W1 [64][64] h/m
    int o = i >> 6, k = i & 63, kt = (k & 32) | Pinv[k & 31];
    float v = ws1[kt * 64 + o];
    u16 h = f2b(v);
    wb[W1H + i] = h; wb[W1M + i] = f2b(v - b2f(h));
  }
  for (int i = gt; i < 1024; i += GS) {          // W2 geo plain bf16 [16][64]
    int o = i >> 6, s = i & 63, kt = (s & 32) | Pinv[s & 31];
    wb[WBG + i] = f2b(ws2[kt * 16 + o]);
  }
  for (int i = gt; i < 64; i += GS) w2c0[i] = ws2[i * 16];   // sigma col f32
  // color layer 0: cin slots 0..15 encd, 16 dead(sigma), 17..31 geo(1..15),
  // 32..47 app, 48..63 zero
  for (int i = gt; i < 4096; i += GS) {
    int o = i >> 6, s = i & 63, kt = (s & 32) | Pinv[s & 31];
    float v = 0.f;
    if (kt < 16) v = wc0[kt * 64 + o];
    else if (kt >= 17 && kt <= 47) v = wc0[(kt - 1) * 64 + o];
    wb[WBC0 + i] = f2b(v);
  }
  for (int i = gt; i < 4096; i += GS) {
    int o = i >> 6, s = i & 63, kt = (s & 32) | Pinv[s & 31];
    wb[WBC1 + i] = f2b(wc1[kt * 64 + o]);
  }
  for (int i = gt; i < 4096; i += GS) {
    int o = i >> 6, s = i & 63, kt = (s & 32) | Pinv[s & 31];
    wb[WBC2 + i] = f2b(wc2[kt * 64 + o]);
  }
  for (int i = gt; i < 1024; i += GS) {
    int o = i >> 6, s = i & 63, kt = (s & 32) | Pinv[s & 31];
    wb[WBC3 + i] = f2b(o < 3 ? wc3[kt * 3 + o] : 0.f);
  }
}

// ---------------- fused encode + half-tile split-MFMA sigma + bf16 color ----------------
// 1 wave/block. LDS: EC 8KB + HB 2KB = 10240 B -> 16 blocks/CU (LDS cap =
// 4 waves/EU). amdgpu_waves_per_eu(4,4) pins the allocator at that occupancy
// so it uses up to 128 VGPRs instead of squeezing to 64 + spilling (R8 lesson:
// VGPR=64, WRITE_SIZE 244MB scratch).
__global__ void __launch_bounds__(64)
__attribute__((amdgpu_waves_per_eu(4, 4)))
point_kernel(const float* __restrict__ rays, const float* __restrict__ tables,
             const u16* __restrict__ wb, const float* __restrict__ w2c0,
             const float* __restrict__ app_table, u16* __restrict__ raw, ResArr RES)
{
  __shared__ char lds[10240];
  char* EC = lds;
  char* HB = lds + 8192;
  const int lane = threadIdx.x;
  const int pBase = blockIdx.x * 64;
  const int q = lane & 15, g = lane >> 4;
  const unsigned swzQ = (unsigned)((q & 7) << 4);
  const unsigned swzMy = (unsigned)((lane & 7) << 4);

  // ---------- phase 1: per-thread hash encode ----------
  const int ptG = pBase + lane;
  const int r = ptG >> 7, s = ptG & (NSAMP - 1);
  const float ox = rays[r * 7 + 0], oy = rays[r * 7 + 1], oz = rays[r * 7 + 2];
  const float dx = rays[r * 7 + 3], dy = rays[r * 7 + 4], dz = rays[r * 7 + 5];
  const int code = (int)rays[r * 7 + 6];
  const float z = 0.5f + (3.5f / 127.f) * (float)s;
  const float x = fmaf(dx, z, ox), y = fmaf(dy, z, oy), w = fmaf(dz, z, oz);
  const bool keep = (x >= -4.f && x <= 4.f && y >= -4.f && y <= 4.f &&
                     w >= -4.f && w <= 4.f);
  const float keepf = keep ? 1.f : 0.f;
  const float xc = fminf(fmaxf(x, -4.f), 4.f);
  const float yc = fminf(fmaxf(y, -4.f), 4.f);
  const float zc = fminf(fmaxf(w, -4.f), 4.f);

  float encp[32];
  #pragma unroll
  for (int l = 0; l < 16; ++l) {
    const float res = RES.r[l];
    const float sc = res * 0.125f;
    const float px = (xc + 4.f) * sc, py = (yc + 4.f) * sc, pz = (zc + 4.f) * sc;
    const float bx = floorf(px), by = floorf(py), bz = floorf(pz);
    const float fx = px - bx, fy = py - by, fz = pz - bz;
    const unsigned ix = (unsigned)bx, iy = (unsigned)by, iz = (unsigned)bz;
    const unsigned hx0 = ix, hx1 = ix + 1u;
    const unsigned hy0 = iy * 2654435761u, hy1 = (iy + 1u) * 2654435761u;
    const unsigned hz0 = iz * 805459861u,  hz1 = (iz + 1u) * 805459861u;
    const float wx0 = 1.f - fx, wy0 = 1.f - fy, wz0 = 1.f - fz;
    const float* tl = tables + (size_t)l * LVL_STRIDE;
    float f0 = 0.f, f1 = 0.f;
    #pragma unroll
    for (int c = 0; c < 8; ++c) {
      const unsigned cx = (c >> 2) & 1, cy = (c >> 1) & 1, cz = c & 1;
      const unsigned idx = ((cx ? hx1 : hx0) ^ (cy ? hy1 : hy0) ^ (cz ? hz1 : hz0)) & TBL_MASK;
      const float cw = (cx ? fx : wx0) * (cy ? fy : wy0) * (cz ? fz : wz0);
      const float2 e = *reinterpret_cast<const float2*>(tl + (size_t)idx * 2);
      f0 = fmaf(cw, e.x, f0);
      f1 = fmaf(cw, e.y, f1);
    }
    encp[2 * l] = f0;
    encp[2 * l + 1] = f1;
  }
  #pragma unroll
  for (int c = 0; c < 8; ++c) {
    float4 u = make_float4(encp[4 * c + 0], encp[4 * c + 1], encp[4 * c + 2], encp[4 * c + 3]);
    *(float4*)(EC + lane * 128 + (((unsigned)(c * 16)) ^ swzMy)) = u;
  }
  MEMBAR();

  // 4-product 2-way-split accumulate (hh, mh, hm, mm)
  auto four = [&](const u16* pH, const u16* pM, bf16x8 bh, bf16x8 bm, f32x4 c) -> f32x4 {
    bf16x8 Ah = *(const bf16x8*)pH, Am = *(const bf16x8*)pM;
    c = __builtin_amdgcn_mfma_f32_16x16x32_bf16(Ah, bh, c, 0, 0, 0);
    c = __builtin_amdgcn_mfma_f32_16x16x32_bf16(Am, bh, c, 0, 0, 0);
    c = __builtin_amdgcn_mfma_f32_16x16x32_bf16(Ah, bm, c, 0, 0, 0);
    c = __builtin_amdgcn_mfma_f32_16x16x32_bf16(Am, bm, c, 0, 0, 0);
    return c;
  };
  // store C half-tile (lane q,g holds ch (m&1)*16+g*4..+3 of point-col q) into HB
  auto stH = [&](int mh, f32x4 c, bool relu) {
    if (relu) {
      c[0] = fmaxf(c[0], 0.f); c[1] = fmaxf(c[1], 0.f);
      c[2] = fmaxf(c[2], 0.f); c[3] = fmaxf(c[3], 0.f);
    }
    *(float4*)(HB + q * 128 + (((unsigned)(mh * 64 + g * 16)) ^ swzQ)) =
        make_float4(c[0], c[1], c[2], c[3]);
  };

  // ---------- phase 2: sigma MLP, per-n, half-tile ping-pong in HB ----------
  float sigv[4];
  #pragma unroll
  for (int n = 0; n < 4; ++n) {
    // B0: 2-way split of enc row (n*16+q)
    bf16x8 B0h, B0m;
    {
      const char* p = EC + (n * 16 + q) * 128;
      float4 a = *(const float4*)(p + (((unsigned)(g * 32)) ^ swzQ));
      float4 b = *(const float4*)(p + (((unsigned)(g * 32 + 16)) ^ swzQ));
      split2_8(a, b, B0h, B0m);
    }
    f32x4 acc1[4];
    #pragma unroll
    for (int m = 0; m < 4; ++m) acc1[m] = f32x4{0.f, 0.f, 0.f, 0.f};

    // L0 half a (h1 ch 0..31) -> HB
    #pragma unroll
    for (int m = 0; m < 2; ++m) {
      const int row = (m * 16 + q) * 32 + g * 8;
      f32x4 c = {0.f, 0.f, 0.f, 0.f};
      c = four(wb + W0H + row, wb + W0M + row, B0h, B0m, c);
      stH(m, c, true);
    }
    MEMBAR();
    // L1 kc=0
    {
      float4 a = *(const float4*)(HB + q * 128 + (((unsigned)(g * 32)) ^ swzQ));
      float4 b = *(const float4*)(HB + q * 128 + (((unsigned)(g * 32 + 16)) ^ swzQ));
      bf16x8 Bh, Bm; split2_8(a, b, Bh, Bm);
      #pragma unroll
      for (int m = 0; m < 4; ++m) {
        const int row = (m * 16 + q) * 64 + g * 8;
        acc1[m] = four(wb + W1H + row, wb + W1M + row, Bh, Bm, acc1[m]);
      }
    }
    MEMBAR();
    // L0 half b (h1 ch 32..63) -> HB
    #pragma unroll
    for (int m = 2; m < 4; ++m) {
      const int row = (m * 16 + q) * 32 + g * 8;
      f32x4 c = {0.f, 0.f, 0.f, 0.f};
      c = four(wb + W0H + row, wb + W0M + row, B0h, B0m, c);
      stH(m & 1, c, true);
    }
    MEMBAR();
    // L1 kc=1
    {
      float4 a = *(const float4*)(HB + q * 128 + (((unsigned)(g * 32)) ^ swzQ));
      float4 b = *(const float4*)(HB + q * 128 + (((unsigned)(g * 32 + 16)) ^ swzQ));
      bf16x8 Bh, Bm; split2_8(a, b, Bh, Bm);
      #pragma unroll
      for (int m = 0; m < 4; ++m) {
        const int row = (m * 16 + q) * 64 + 32 + g * 8;
        acc1[m] = four(wb + W1H + row, wb + W1M + row, Bh, Bm, acc1[m]);
      }
    }
    #pragma unroll
    for (int m = 0; m < 4; ++m) {
      acc1[m][0] = fmaxf(acc1[m][0], 0.f); acc1[m][1] = fmaxf(acc1[m][1], 0.f);
      acc1[m][2] = fmaxf(acc1[m][2], 0.f); acc1[m][3] = fmaxf(acc1[m][3], 0.f);
    }
    MEMBAR();
    // L2: geo (plain bf16) + sigma dot (f32), via the same half-tile HB
    f32x4 gc = {0.f, 0.f, 0.f, 0.f};
    float sp = 0.f;
    stH(0, acc1[0], false); stH(1, acc1[1], false);
    MEMBAR();
    {
      float4 a = *(const float4*)(HB + q * 128 + (((unsigned)(g * 32)) ^ swzQ));
      float4 b = *(const float4*)(HB + q * 128 + (((unsigned)(g * 32 + 16)) ^ swzQ));
      bf16x8 Bg = tob8(a, b);
      gc = __builtin_amdgcn_mfma_f32_16x16x32_bf16(
          *(const bf16x8*)(wb + WBG + q * 64 + g * 8), Bg, gc, 0, 0, 0);
      float4 wa = *(const float4*)(w2c0 + g * 8);
      float4 wb4 = *(const float4*)(w2c0 + g * 8 + 4);
      sp = fmaf(a.x, wa.x, sp); sp = fmaf(a.y, wa.y, sp);
      sp = fmaf(a.z, wa.z, sp); sp = fmaf(a.w, wa.w, sp);
      sp = fmaf(b.x, wb4.x, sp); sp = fmaf(b.y, wb4.y, sp);
      sp = fmaf(b.z, wb4.z, sp); sp = fmaf(b.w, wb4.w, sp);
    }
    MEMBAR();
    stH(0, acc1[2], false); stH(1, acc1[3], false);
    MEMBAR();
    {
      float4 a = *(const float4*)(HB + q * 128 + (((unsigned)(g * 32)) ^ swzQ));
      float4 b = *(const float4*)(HB + q * 128 + (((unsigned)(g * 32 + 16)) ^ swzQ));
      bf16x8 Bg = tob8(a, b);
      gc = __builtin_amdgcn_mfma_f32_16x16x32_bf16(
          *(const bf16x8*)(wb + WBG + q * 64 + 32 + g * 8), Bg, gc, 0, 0, 0);
      float4 wa = *(const float4*)(w2c0 + 32 + g * 8);
      float4 wb4 = *(const float4*)(w2c0 + 32 + g * 8 + 4);
      sp = fmaf(a.x, wa.x, sp); sp = fmaf(a.y, wa.y, sp);
      sp = fmaf(a.z, wa.z, sp); sp = fmaf(a.w, wa.w, sp);
      sp = fmaf(b.x, wb4.x, sp); sp = fmaf(b.y, wb4.y, sp);
      sp = fmaf(b.z, wb4.z, sp); sp = fmaf(b.w, wb4.w, sp);
    }
    // geo (no relu) -> color slots 16+4g..19+4g of row n*16+q (slot16 weight=0)
    {
      uint2 u; u.x = pack2(gc[0], gc[1]); u.y = pack2(gc[2], gc[3]);
      *(uint2*)(EC + (n * 16 + q) * 128 + (((unsigned)(32 + 8 * g)) ^ swzQ)) = u;
    }
    sp += __shfl_xor(sp, 16);
    sp += __shfl_xor(sp, 32);
    sigv[n] = sp * __shfl(keepf, n * 16 + q);
    MEMBAR();
  }

  // own row: encd slots 0..15, app 32..47, zeros 48..63
  {
    const float xx = dx * dx, yy = dy * dy, zz2 = dz * dz;
    const float xy = dx * dy, yz = dy * dz, xz = dx * dz;
    float e0 = 0.28209479177387814f;
    float e1 = -0.4886025119029199f * dy;
    float e2 = 0.4886025119029199f * dz;
    float e3 = -0.4886025119029199f * dx;
    float e4 = 1.0925484305920792f * xy;
    float e5 = -1.0925484305920792f * yz;
    float e6 = 0.31539156525252005f * (2.f * zz2 - xx - yy);
    float e7 = -1.0925484305920792f * xz;
    float e8 = 0.5462742152960396f * (xx - yy);
    float e9 = -0.5900435899266435f * dy * (3.f * xx - yy);
    float e10 = 2.890611442640554f * xy * dz;
    float e11 = -0.4570457994644658f * dy * (4.f * zz2 - xx - yy);
    float e12 = 0.3731763325901154f * dz * (2.f * zz2 - 3.f * xx - 3.f * yy);
    float e13 = -0.4570457994644658f * dx * (4.f * zz2 - xx - yy);
    float e14 = 1.445305721320277f * dz * (xx - yy);
    float e15 = -0.5900435899266435f * dx * (xx - 3.f * yy);
    uint4 u0; u0.x = pack2(e0, e1);  u0.y = pack2(e2, e3);  u0.z = pack2(e4, e5);  u0.w = pack2(e6, e7);
    uint4 u1; u1.x = pack2(e8, e9);  u1.y = pack2(e10, e11); u1.z = pack2(e12, e13); u1.w = pack2(e14, e15);
    *(uint4*)(EC + lane * 128 + (0u ^ swzMy)) = u0;
    *(uint4*)(EC + lane * 128 + (16u ^ swzMy)) = u1;
    const float4* ap = (const float4*)(app_table + (size_t)code * 16);
    float4 a0 = ap[0], a1 = ap[1], a2 = ap[2], a3 = ap[3];
    uint4 v0; v0.x = pack2(a0.x, a0.y); v0.y = pack2(a0.z, a0.w); v0.z = pack2(a1.x, a1.y); v0.w = pack2(a1.z, a1.w);
    uint4 v1; v1.x = pack2(a2.x, a2.y); v1.y = pack2(a2.z, a2.w); v1.z = pack2(a3.x, a3.y); v1.w = pack2(a3.z, a3.w);
    *(uint4*)(EC + lane * 128 + (64u ^ swzMy)) = v0;
    *(uint4*)(EC + lane * 128 + (80u ^ swzMy)) = v1;
    uint4 zv; zv.x = 0u; zv.y = 0u; zv.z = 0u; zv.w = 0u;
    *(uint4*)(EC + lane * 128 + (96u ^ swzMy)) = zv;
    *(uint4*)(EC + lane * 128 + (112u ^ swzMy)) = zv;
  }
  MEMBAR();

  // ---------- phase 3: color MFMA MLP (plain bf16, proven) ----------
  auto rdB = [&](int n, int kc) -> bf16x8 {
    return *(const bf16x8*)(EC + (n * 16 + q) * 128 + (((unsigned)(kc * 64 + g * 16)) ^ swzQ));
  };
  auto ldA = [&](const u16* Wp, int row, int kc) -> bf16x8 {
    return *(const bf16x8*)(Wp + row * 64 + kc * 32 + g * 8);
  };
  auto wrC = [&](int n, int slot0, f32x4 c) {
    c[0] = fmaxf(c[0], 0.f); c[1] = fmaxf(c[1], 0.f);
    c[2] = fmaxf(c[2], 0.f); c[3] = fmaxf(c[3], 0.f);
    uint2 u; u.x = pack2(c[0], c[1]); u.y = pack2(c[2], c[3]);
    *(uint2*)(EC + (n * 16 + q) * 128 + (((unsigned)(slot0 * 2)) ^ swzQ)) = u;
  };
  auto layer64 = [&](const u16* Wp) {
    bf16x8 A[4][2];
    #pragma unroll
    for (int m = 0; m < 4; ++m) {
      A[m][0] = ldA(Wp, m * 16 + q, 0);
      A[m][1] = ldA(Wp, m * 16 + q, 1);
    }
    #pragma unroll
    for (int n = 0; n < 4; ++n) {
      bf16x8 b0 = rdB(n, 0), b1 = rdB(n, 1);
      #pragma unroll
      for (int m = 0; m < 4; ++m) {
        f32x4 c = {0.f, 0.f, 0.f, 0.f};
        c = __builtin_amdgcn_mfma_f32_16x16x32_bf16(A[m][0], b0, c, 0, 0, 0);
        c = __builtin_amdgcn_mfma_f32_16x16x32_bf16(A[m][1], b1, c, 0, 0, 0);
        wrC(n, m * 16 + g * 4, c);
      }
    }
    MEMBAR();
  };

  layer64(wb + WBC0);
  layer64(wb + WBC1);
  layer64(wb + WBC2);

  {
    const u16* Wp = wb + WBC3;
    bf16x8 A0 = ldA(Wp, q, 0), A1 = ldA(Wp, q, 1);
    #pragma unroll
    for (int n = 0; n < 4; ++n) {
      bf16x8 b0 = rdB(n, 0), b1 = rdB(n, 1);
      f32x4 c = {0.f, 0.f, 0.f, 0.f};
      c = __builtin_amdgcn_mfma_f32_16x16x32_bf16(A0, b0, c, 0, 0, 0);
      c = __builtin_amdgcn_mfma_f32_16x16x32_bf16(A1, b1, c, 0, 0, 0);
      if (g == 0) {
        uint2 o; o.x = pack2(c[0], c[1]); o.y = pack2(c[2], sigv[n]);
        *(uint2*)(raw + (size_t)(pBase + n * 16 + q) * 4) = o;
      }
    }
  }
}

// ---------------- per-ray compositing (single merged pass) ----------------
__global__ void __launch_bounds__(64)
render_kernel(const float* __restrict__ rays, const u16* __restrict__ raw,
              float* __restrict__ out)
{
  const int r = blockIdx.x * 64 + threadIdx.x;
  if (r >= NRAYS) return;
  const float dx = rays[r * 7 + 3], dy = rays[r * 7 + 4], dz = rays[r * 7 + 5];
  const float nrm = sqrtf(dx * dx + dy * dy + dz * dz);
  const float dstep = 3.5f / 127.f;
  const ushort4* rp = reinterpret_cast<const ushort4*>(raw) + (size_t)r * NSAMP;

  float T = 1.f, sumw = 0.f, sumwz = 0.f, cm0 = 0.f, cm1 = 0.f, cm2 = 0.f;
  float S1 = 0.f, S2 = 0.f;
  for (int s = 0; s < NSAMP; ++s) {
    const ushort4 rw = rp[s];
    const float dist = ((s < NSAMP - 1) ? dstep : 1e10f) * nrm;
    const float sigv = fmaxf(b2f(rw.w), 0.f);
    const float alpha = 1.f - expf(-sigv * dist);
    const float wgt = alpha * T;
    T *= (1.f - alpha + 1e-10f);
    const float zv = 0.5f + dstep * (float)s;
    sumw += wgt;
    sumwz = fmaf(wgt, zv, sumwz);
    cm0 = fmaf(wgt, sigmoidf_(b2f(rw.x)), cm0);
    cm1 = fmaf(wgt, sigmoidf_(b2f(rw.y)), cm1);
    cm2 = fmaf(wgt, sigmoidf_(b2f(rw.z)), cm2);
    const float qv = fmaxf(wgt, 1e-12f);
    S1 += qv;
    S2 = fmaf(qv, logf(qv), S2);
  }
  const float plast = fmaxf(1.f - sumw + 1e-6f, 1e-12f);
  S1 += plast;
  S2 = fmaf(plast, logf(plast), S2);
  const float ent = logf(S1) - S2 / S1;

  out[r * 3 + 0] = cm0;
  out[r * 3 + 1] = cm1;
  out[r * 3 + 2] = cm2;
  out[NRAYS * 3 + r] = sumwz;
  out[NRAYS * 4 + r] = ent;
}

extern "C" void kernel_launch(void* const* d_in, const int* in_sizes, int n_in,
                              void* d_out, int out_size, void* d_ws, size_t ws_size,
                              hipStream_t stream)
{
  const float* rays   = (const float*)d_in[0];
  const float* tables = (const float*)d_in[2];
  const float* ws0    = (const float*)d_in[3];
  const float* ws1    = (const float*)d_in[4];
  const float* ws2    = (const float*)d_in[5];
  const float* wc0    = (const float*)d_in[6];
  const float* wc1    = (const float*)d_in[7];
  const float* wc2    = (const float*)d_in[8];
  const float* wc3    = (const float*)d_in[9];
  const float* app    = (const float*)d_in[10];

  u16* wb    = (u16*)d_ws;
  float* w2c0 = (float*)((char*)d_ws + W2C0_OFF);
  u16* raw   = (u16*)((char*)d_ws + RAW_OFF);
  float* out = (float*)d_out;

  ResArr RES;
  const double b = exp((log(512.0) - log(16.0)) / 15.0);
  for (int l = 0; l < 16; ++l) RES.r[l] = (float)floor(16.0 * pow(b, (double)l));

  hipLaunchKernelGGL(prep_kernel, dim3(8), dim3(256), 0, stream,
                     ws0, ws1, ws2, wc0, wc1, wc2, wc3, wb, w2c0);
  hipLaunchKernelGGL(point_kernel, dim3(NPTS / 64), dim3(64), 0, stream,
                     rays, tables, wb, w2c0, app, raw, RES);
  hipLaunchKernelGGL(render_kernel, dim3(NRAYS / 64), dim3(64), 0, stream,
                     rays, raw, out);
}